// Round 1
// baseline (452.697 us; speedup 1.0000x reference)
//
#include <hip/hip_runtime.h>
#include <cmath>

#define R_TOT 4096   // B*S rows
#define HID   768
#define NHEAD 12
#define HDIM  64
#define SEQ   512
#define BATCH 8

#if defined(__has_builtin)
#  if __has_builtin(__builtin_amdgcn_sdot4)
#    define USE_SDOT4 1
#  endif
#endif

__device__ __forceinline__ int dot4(int a, int b, int c) {
#ifdef USE_SDOT4
  return __builtin_amdgcn_sdot4(a, b, c, false);
#else
  c += (int)(signed char)(a)       * (int)(signed char)(b);
  c += (int)(signed char)(a >> 8)  * (int)(signed char)(b >> 8);
  c += (int)(signed char)(a >> 16) * (int)(signed char)(b >> 16);
  c += (int)(signed char)(a >> 24) * (int)(signed char)(b >> 24);
  return c;
#endif
}

// ---------------- PLA coefficients (host, replicates np.polyfit in f64) ----
struct PlaConsts { float m[12]; float c[12]; float b[13]; };

static PlaConsts build_pla() {
  PlaConsts pc;
  const int NPTS = 1001;
  static double xs[NPTS], ys[NPTS];
  const double step = 10.0 / 1000.0;              // np.linspace step
  for (int j = 0; j < NPTS; ++j) xs[j] = (double)j * step + (-10.0);
  xs[NPTS - 1] = 0.0;                              // linspace forces endpoint
  for (int j = 0; j < NPTS; ++j) ys[j] = std::exp(xs[j]);
  double bnd[13];
  const double step2 = 10.0 / 12.0;
  for (int k = 0; k < 13; ++k) bnd[k] = (double)k * step2 + (-10.0);
  bnd[12] = 0.0;
  for (int i = 0; i < 12; ++i) {
    const double a = bnd[i], bb = bnd[i + 1];
    double sx = 0, sy = 0; int n = 0;
    for (int j = 0; j < NPTS; ++j)
      if (xs[j] >= a && xs[j] <= bb) { sx += xs[j]; sy += ys[j]; ++n; }
    const double xm = sx / n, ym = sy / n;
    double sxx = 0, sxy = 0;
    for (int j = 0; j < NPTS; ++j)
      if (xs[j] >= a && xs[j] <= bb) {
        const double dx = xs[j] - xm;
        sxx += dx * dx; sxy += dx * (ys[j] - ym);
      }
    const double m = sxy / sxx;
    pc.m[i] = (float)m;
    pc.c[i] = (float)(ym - m * xm);
  }
  for (int k = 0; k < 13; ++k) pc.b[k] = (float)bnd[k];
  return pc;
}
static const PlaConsts g_pla = build_pla();

// ---------------- per-row abs-max int8 quantization -----------------------
__global__ __launch_bounds__(256)
void quant_rows(const float* __restrict__ src, int ncols,
                signed char* __restrict__ qout, float* __restrict__ sout) {
  const int row = blockIdx.x;
  const float* x = src + (size_t)row * ncols;
  float m = 0.f;
  for (int c = threadIdx.x; c < ncols; c += 256)
    m = fmaxf(m, fabsf(x[c]));
  #pragma unroll
  for (int off = 32; off; off >>= 1) m = fmaxf(m, __shfl_xor(m, off));
  __shared__ float red[4];
  const int lane = threadIdx.x & 63, wv = threadIdx.x >> 6;
  if (lane == 0) red[wv] = m;
  __syncthreads();
  if (threadIdx.x == 0) {
    float mm = fmaxf(fmaxf(red[0], red[1]), fmaxf(red[2], red[3]));
    float s = mm / 127.0f;
    if (s == 0.f) s = 1.f;
    red[0] = s;
    sout[row] = s;
  }
  __syncthreads();
  const float s = red[0];
  for (int c = threadIdx.x; c < ncols; c += 256) {
    float q = rintf(x[c] / s);
    q = fminf(fmaxf(q, -127.f), 127.f);
    qout[(size_t)row * ncols + c] = (signed char)(int)q;
  }
}

// ---------------- int8 GEMM: out = (qx.qw^T)*sx*sw + bias -----------------
// 64x64 tile, 256 threads, 4x4 micro-tile, k-major LDS, sdot4 inner loop.
// HEADQ: fuse per-head (64-col) quantization, write bhsd int8 + scales.
template <bool HEADQ>
__global__ __launch_bounds__(256)
void proj_kernel(const signed char* __restrict__ qx, const float* __restrict__ sx,
                 const signed char* __restrict__ qw, const float* __restrict__ sw,
                 const float* __restrict__ bias,
                 signed char* __restrict__ qo, float* __restrict__ so,
                 float* __restrict__ fo) {
  __shared__ __align__(16) int Asm[16][68];  // [kk][row], pad for banks, 272B rows keep int4 align
  __shared__ __align__(16) int Bsm[16][68];
  const int tid = threadIdx.x;
  const int tx = tid & 15, ty = tid >> 4;
  const int row0 = blockIdx.x * 64, col0 = blockIdx.y * 64;
  const int lr = tid >> 2;   // 0..63 tile row to stage
  const int seg = tid & 3;   // 16B segment
  int acc[4][4] = {};
  for (int k0 = 0; k0 < HID; k0 += 64) {
    const int4 av = *(const int4*)(qx + (size_t)(row0 + lr) * HID + k0 + seg * 16);
    const int4 bv = *(const int4*)(qw + (size_t)(col0 + lr) * HID + k0 + seg * 16);
    Asm[seg * 4 + 0][lr] = av.x; Asm[seg * 4 + 1][lr] = av.y;
    Asm[seg * 4 + 2][lr] = av.z; Asm[seg * 4 + 3][lr] = av.w;
    Bsm[seg * 4 + 0][lr] = bv.x; Bsm[seg * 4 + 1][lr] = bv.y;
    Bsm[seg * 4 + 2][lr] = bv.z; Bsm[seg * 4 + 3][lr] = bv.w;
    __syncthreads();
    #pragma unroll
    for (int kk = 0; kk < 16; ++kk) {
      const int4 a4 = *(const int4*)&Asm[kk][ty * 4];
      const int4 b4 = *(const int4*)&Bsm[kk][tx * 4];
      const int a[4] = {a4.x, a4.y, a4.z, a4.w};
      const int b[4] = {b4.x, b4.y, b4.z, b4.w};
      #pragma unroll
      for (int i = 0; i < 4; ++i)
        #pragma unroll
        for (int j = 0; j < 4; ++j)
          acc[i][j] = dot4(a[i], b[j], acc[i][j]);
    }
    __syncthreads();
  }
  float vals[4][4];
  float sxr[4];
  #pragma unroll
  for (int i = 0; i < 4; ++i) sxr[i] = sx[row0 + ty * 4 + i];
  #pragma unroll
  for (int j = 0; j < 4; ++j) {
    const float swc = sw[col0 + tx * 4 + j];
    const float bc = bias[col0 + tx * 4 + j];
    #pragma unroll
    for (int i = 0; i < 4; ++i)
      vals[i][j] = (float)acc[i][j] * (sxr[i] * swc) + bc;
  }
  if (HEADQ) {
    const int h = blockIdx.y;  // grid.y == NHEAD, 64 cols == one head
    #pragma unroll
    for (int i = 0; i < 4; ++i) {
      float mrow = 0.f;
      #pragma unroll
      for (int j = 0; j < 4; ++j) mrow = fmaxf(mrow, fabsf(vals[i][j]));
      #pragma unroll
      for (int off = 1; off < 16; off <<= 1) mrow = fmaxf(mrow, __shfl_xor(mrow, off));
      float s = mrow / 127.0f;
      if (s == 0.f) s = 1.f;
      const int r = row0 + ty * 4 + i;
      const int bidx = r / SEQ, sidx = r % SEQ;
      const size_t rowidx = ((size_t)bidx * NHEAD + h) * SEQ + sidx;
      unsigned int pack = 0;
      #pragma unroll
      for (int j = 0; j < 4; ++j) {
        float q = fminf(fmaxf(rintf(vals[i][j] / s), -127.f), 127.f);
        pack |= ((unsigned int)(unsigned char)(signed char)(int)q) << (8 * j);
      }
      *(unsigned int*)(qo + rowidx * HDIM + tx * 4) = pack;
      if (tx == 0) so[rowidx] = s;
    }
  } else {
    #pragma unroll
    for (int i = 0; i < 4; ++i) {
      const int r = row0 + ty * 4 + i;
      *(float4*)(fo + (size_t)r * HID + col0 + tx * 4) =
          make_float4(vals[i][0], vals[i][1], vals[i][2], vals[i][3]);
    }
  }
}

// ---------------- fused attention: QK^T -> PLA softmax -> quant -> PV -----
__global__ __launch_bounds__(256)
void attn_kernel(const signed char* __restrict__ qq, const float* __restrict__ qss,
                 const signed char* __restrict__ qk, const float* __restrict__ kss,
                 const signed char* __restrict__ qv, const float* __restrict__ vss,
                 float* __restrict__ ctx, const PlaConsts pc) {
  __shared__ float sc[16][516];   // scores/probs, +4 pad breaks bank conflicts
  __shared__ int qrow[16][16];
  __shared__ float qscale[16];
  __shared__ float kscale[512];
  __shared__ float vscale[512];
  const int tid = threadIdx.x;
  const int q0 = blockIdx.x * 16;
  const int h = blockIdx.y, b = blockIdx.z;
  const size_t hb = (size_t)b * NHEAD + h;
  const signed char* qkh = qk + hb * SEQ * HDIM;
  const signed char* qvh = qv + hb * SEQ * HDIM;
  ((int*)qrow)[tid] = ((const int*)(qq + (hb * SEQ + q0) * HDIM))[tid];
  if (tid < 16) qscale[tid] = qss[hb * SEQ + q0 + tid];
  kscale[tid] = kss[hb * SEQ + tid];
  kscale[tid + 256] = kss[hb * SEQ + tid + 256];
  vscale[tid] = vss[hb * SEQ + tid];
  vscale[tid + 256] = vss[hb * SEQ + tid + 256];
  __syncthreads();
  const int qr = tid >> 4;    // q row 0..15
  const int ksl = tid & 15;   // k slice
  int a[16];
  #pragma unroll
  for (int i = 0; i < 16; ++i) a[i] = qrow[qr][i];
  const float qsc = qscale[qr];
  float mx = -3.0e38f;
  for (int jj = 0; jj < 32; ++jj) {
    const int kc = jj * 16 + ksl;
    const int4* kp4 = (const int4*)(qkh + (size_t)kc * HDIM);
    const int4 kA = kp4[0], kB = kp4[1], kC = kp4[2], kD = kp4[3];
    const int kk[16] = {kA.x, kA.y, kA.z, kA.w, kB.x, kB.y, kB.z, kB.w,
                        kC.x, kC.y, kC.z, kC.w, kD.x, kD.y, kD.z, kD.w};
    int acc = 0;
    #pragma unroll
    for (int i = 0; i < 16; ++i) acc = dot4(a[i], kk[i], acc);
    const float v = (float)acc * (qsc * kscale[kc] * 0.125f);
    sc[qr][kc] = v;
    mx = fmaxf(mx, v);
  }
  #pragma unroll
  for (int off = 1; off < 16; off <<= 1) mx = fmaxf(mx, __shfl_xor(mx, off));
  float sum = 0.f, amax = 0.f;
  for (int jj = 0; jj < 32; ++jj) {
    const int kc = jj * 16 + ksl;
    const float sh = sc[qr][kc] - mx;
    float t = rintf(sh * 67108864.0f);               // 2^26 fixed point
    t = fminf(fmaxf(t, -2147483648.0f), 2147483648.0f);
    const float x = t * (1.0f / 67108864.0f);        // exact (pow2)
    const float xc = fminf(fmaxf(x, -10.0f), 0.0f);
    int idx = -1;
    #pragma unroll
    for (int i = 0; i < 13; ++i) idx += (xc >= pc.b[i]) ? 1 : 0;
    idx = max(0, min(idx, 11));
    const float e = __fadd_rn(__fmul_rn(pc.m[idx], xc), pc.c[idx]);
    sc[qr][kc] = e;
    sum += e;
    amax = fmaxf(amax, fabsf(e));
  }
  #pragma unroll
  for (int off = 1; off < 16; off <<= 1) {
    sum += __shfl_xor(sum, off);
    amax = fmaxf(amax, __shfl_xor(amax, off));
  }
  const float denom = __fadd_rn(sum, 1e-9f);
  const float pmax = amax / denom;                   // == max|p| (monotone div)
  float ps = pmax / 127.0f;
  if (ps == 0.f) ps = 1.f;
  for (int jj = 0; jj < 32; ++jj) {
    const int kc = jj * 16 + ksl;
    const float p = sc[qr][kc] / denom;
    const float qf = fminf(fmaxf(rintf(p / ps), -127.f), 127.f);
    sc[qr][kc] = __fmul_rn(qf, ps);                  // fake-quantized prob
  }
  __syncthreads();
  // ctx = probs @ quantize(v); thread: row qr2, 4 consecutive d
  const int dg = tid & 15;
  const int qr2 = tid >> 4;
  float o0 = 0, o1 = 0, o2 = 0, o3 = 0;
  for (int k = 0; k < SEQ; ++k) {
    const float p = sc[qr2][k];
    const float vsk = vscale[k];
    const int vp = *(const int*)(qvh + (size_t)k * HDIM + dg * 4);
    o0 += p * ((float)(signed char)(vp)        * vsk);
    o1 += p * ((float)(signed char)(vp >> 8)   * vsk);
    o2 += p * ((float)(signed char)(vp >> 16)  * vsk);
    o3 += p * ((float)(signed char)(vp >> 24)  * vsk);
  }
  const size_t orow = ((size_t)b * SEQ + q0 + qr2) * HID + (size_t)h * HDIM + dg * 4;
  *(float4*)(ctx + orow) = make_float4(o0, o1, o2, o3);
}

// --------------------------------------------------------------------------
extern "C" void kernel_launch(void* const* d_in, const int* in_sizes, int n_in,
                              void* d_out, int out_size, void* d_ws, size_t ws_size,
                              hipStream_t stream) {
  (void)in_sizes; (void)n_in; (void)out_size; (void)ws_size;
  const float* hs = (const float*)d_in[0];
  const float* Wq = (const float*)d_in[1];
  const float* bq = (const float*)d_in[2];
  const float* Wk = (const float*)d_in[3];
  const float* bk = (const float*)d_in[4];
  const float* Wv = (const float*)d_in[5];
  const float* bv = (const float*)d_in[6];
  const float* Wo = (const float*)d_in[7];
  const float* bo = (const float*)d_in[8];
  float* out = (float*)d_out;

  char* ws = (char*)d_ws;
  size_t off = 0;
  auto alloc = [&](size_t bytes) -> char* {
    char* p = ws + off;
    off += (bytes + 255) & ~(size_t)255;
    return p;
  };
  signed char* qx  = (signed char*)alloc((size_t)R_TOT * HID);
  float*       sx  = (float*)alloc((size_t)R_TOT * 4);
  signed char* qwq = (signed char*)alloc((size_t)HID * HID);
  signed char* qwk = (signed char*)alloc((size_t)HID * HID);
  signed char* qwv = (signed char*)alloc((size_t)HID * HID);
  signed char* qwo = (signed char*)alloc((size_t)HID * HID);
  float*       swq = (float*)alloc((size_t)HID * 4);
  float*       swk = (float*)alloc((size_t)HID * 4);
  float*       swv = (float*)alloc((size_t)HID * 4);
  float*       swo = (float*)alloc((size_t)HID * 4);
  signed char* qqd = (signed char*)alloc((size_t)R_TOT * HID);
  float*       qqs = (float*)alloc((size_t)BATCH * NHEAD * SEQ * 4);
  signed char* qkd = (signed char*)alloc((size_t)R_TOT * HID);
  float*       qks = (float*)alloc((size_t)BATCH * NHEAD * SEQ * 4);
  signed char* qvd = (signed char*)alloc((size_t)R_TOT * HID);
  float*       qvs = (float*)alloc((size_t)BATCH * NHEAD * SEQ * 4);
  float*       ctx = (float*)alloc((size_t)R_TOT * HID * 4);
  signed char* qc  = (signed char*)alloc((size_t)R_TOT * HID);
  float*       scs = (float*)alloc((size_t)R_TOT * 4);

  quant_rows<<<R_TOT, 256, 0, stream>>>(hs, HID, qx, sx);
  quant_rows<<<HID, 256, 0, stream>>>(Wq, HID, qwq, swq);
  quant_rows<<<HID, 256, 0, stream>>>(Wk, HID, qwk, swk);
  quant_rows<<<HID, 256, 0, stream>>>(Wv, HID, qwv, swv);
  quant_rows<<<HID, 256, 0, stream>>>(Wo, HID, qwo, swo);

  const dim3 pg(R_TOT / 64, HID / 64);
  proj_kernel<true><<<pg, 256, 0, stream>>>(qx, sx, qwq, swq, bq, qqd, qqs, nullptr);
  proj_kernel<true><<<pg, 256, 0, stream>>>(qx, sx, qwk, swk, bk, qkd, qks, nullptr);
  proj_kernel<true><<<pg, 256, 0, stream>>>(qx, sx, qwv, swv, bv, qvd, qvs, nullptr);

  attn_kernel<<<dim3(SEQ / 16, NHEAD, BATCH), 256, 0, stream>>>(
      qqd, qqs, qkd, qks, qvd, qvs, ctx, g_pla);

  quant_rows<<<R_TOT, 256, 0, stream>>>(ctx, HID, qc, scs);
  proj_kernel<false><<<pg, 256, 0, stream>>>(qc, scs, qwo, swo, bo, nullptr, nullptr, out);
}

// Round 2
// 269.444 us; speedup vs baseline: 1.6801x; 1.6801x over previous
//
#include <hip/hip_runtime.h>
#include <cmath>

#define R_TOT 4096   // B*S rows
#define HID   768
#define NHEAD 12
#define HDIM  64
#define SEQ   512
#define BATCH 8

#if defined(__has_builtin)
#  if __has_builtin(__builtin_amdgcn_sdot4)
#    define USE_SDOT4 1
#  endif
#endif

typedef int   v4i  __attribute__((ext_vector_type(4)));
typedef float v4f  __attribute__((ext_vector_type(4)));
typedef _Float16 half8 __attribute__((ext_vector_type(8)));

__device__ __forceinline__ int dot4(int a, int b, int c) {
#ifdef USE_SDOT4
  return __builtin_amdgcn_sdot4(a, b, c, false);
#else
  c += (int)(signed char)(a)       * (int)(signed char)(b);
  c += (int)(signed char)(a >> 8)  * (int)(signed char)(b >> 8);
  c += (int)(signed char)(a >> 16) * (int)(signed char)(b >> 16);
  c += (int)(signed char)(a >> 24) * (int)(signed char)(b >> 24);
  return c;
#endif
}

// ---------------- PLA coefficients (host, replicates np.polyfit in f64) ----
struct PlaConsts { float m[12]; float c[12]; float b[13]; };

static PlaConsts build_pla() {
  PlaConsts pc;
  const int NPTS = 1001;
  static double xs[NPTS], ys[NPTS];
  const double step = 10.0 / 1000.0;
  for (int j = 0; j < NPTS; ++j) xs[j] = (double)j * step + (-10.0);
  xs[NPTS - 1] = 0.0;
  for (int j = 0; j < NPTS; ++j) ys[j] = std::exp(xs[j]);
  double bnd[13];
  const double step2 = 10.0 / 12.0;
  for (int k = 0; k < 13; ++k) bnd[k] = (double)k * step2 + (-10.0);
  bnd[12] = 0.0;
  for (int i = 0; i < 12; ++i) {
    const double a = bnd[i], bb = bnd[i + 1];
    double sx = 0, sy = 0; int n = 0;
    for (int j = 0; j < NPTS; ++j)
      if (xs[j] >= a && xs[j] <= bb) { sx += xs[j]; sy += ys[j]; ++n; }
    const double xm = sx / n, ym = sy / n;
    double sxx = 0, sxy = 0;
    for (int j = 0; j < NPTS; ++j)
      if (xs[j] >= a && xs[j] <= bb) {
        const double dx = xs[j] - xm;
        sxx += dx * dx; sxy += dx * (ys[j] - ym);
      }
    const double m = sxy / sxx;
    pc.m[i] = (float)m;
    pc.c[i] = (float)(ym - m * xm);
  }
  for (int k = 0; k < 13; ++k) pc.b[k] = (float)bnd[k];
  return pc;
}
static const PlaConsts g_pla = build_pla();

// ---------------- per-row abs-max int8 quantization -----------------------
__global__ __launch_bounds__(256)
void quant_rows(const float* __restrict__ src, int ncols,
                signed char* __restrict__ qout, float* __restrict__ sout) {
  const int row = blockIdx.x;
  const float* x = src + (size_t)row * ncols;
  float m = 0.f;
  for (int c = threadIdx.x; c < ncols; c += 256)
    m = fmaxf(m, fabsf(x[c]));
  #pragma unroll
  for (int off = 32; off; off >>= 1) m = fmaxf(m, __shfl_xor(m, off));
  __shared__ float red[4];
  const int lane = threadIdx.x & 63, wv = threadIdx.x >> 6;
  if (lane == 0) red[wv] = m;
  __syncthreads();
  if (threadIdx.x == 0) {
    float mm = fmaxf(fmaxf(red[0], red[1]), fmaxf(red[2], red[3]));
    float s = mm / 127.0f;
    if (s == 0.f) s = 1.f;
    red[0] = s;
    sout[row] = s;
  }
  __syncthreads();
  const float s = red[0];
  for (int c = threadIdx.x; c < ncols; c += 256) {
    float q = rintf(x[c] / s);
    q = fminf(fmaxf(q, -127.f), 127.f);
    qout[(size_t)row * ncols + c] = (signed char)(int)q;
  }
}

// ---------------- int8 GEMM: out = (qx.qw^T)*sx*sw + bias -----------------
template <bool HEADQ>
__global__ __launch_bounds__(256)
void proj_kernel(const signed char* __restrict__ qx, const float* __restrict__ sx,
                 const signed char* __restrict__ qw, const float* __restrict__ sw,
                 const float* __restrict__ bias,
                 signed char* __restrict__ qo, float* __restrict__ so,
                 float* __restrict__ fo) {
  __shared__ __align__(16) int Asm[16][68];
  __shared__ __align__(16) int Bsm[16][68];
  const int tid = threadIdx.x;
  const int tx = tid & 15, ty = tid >> 4;
  const int row0 = blockIdx.x * 64, col0 = blockIdx.y * 64;
  const int lr = tid >> 2;
  const int seg = tid & 3;
  int acc[4][4] = {};
  for (int k0 = 0; k0 < HID; k0 += 64) {
    const int4 av = *(const int4*)(qx + (size_t)(row0 + lr) * HID + k0 + seg * 16);
    const int4 bv = *(const int4*)(qw + (size_t)(col0 + lr) * HID + k0 + seg * 16);
    Asm[seg * 4 + 0][lr] = av.x; Asm[seg * 4 + 1][lr] = av.y;
    Asm[seg * 4 + 2][lr] = av.z; Asm[seg * 4 + 3][lr] = av.w;
    Bsm[seg * 4 + 0][lr] = bv.x; Bsm[seg * 4 + 1][lr] = bv.y;
    Bsm[seg * 4 + 2][lr] = bv.z; Bsm[seg * 4 + 3][lr] = bv.w;
    __syncthreads();
    #pragma unroll
    for (int kk = 0; kk < 16; ++kk) {
      const int4 a4 = *(const int4*)&Asm[kk][ty * 4];
      const int4 b4 = *(const int4*)&Bsm[kk][tx * 4];
      const int a[4] = {a4.x, a4.y, a4.z, a4.w};
      const int b[4] = {b4.x, b4.y, b4.z, b4.w};
      #pragma unroll
      for (int i = 0; i < 4; ++i)
        #pragma unroll
        for (int j = 0; j < 4; ++j)
          acc[i][j] = dot4(a[i], b[j], acc[i][j]);
    }
    __syncthreads();
  }
  float vals[4][4];
  float sxr[4];
  #pragma unroll
  for (int i = 0; i < 4; ++i) sxr[i] = sx[row0 + ty * 4 + i];
  #pragma unroll
  for (int j = 0; j < 4; ++j) {
    const float swc = sw[col0 + tx * 4 + j];
    const float bc = bias[col0 + tx * 4 + j];
    #pragma unroll
    for (int i = 0; i < 4; ++i)
      vals[i][j] = (float)acc[i][j] * (sxr[i] * swc) + bc;
  }
  if (HEADQ) {
    const int h = blockIdx.y;
    #pragma unroll
    for (int i = 0; i < 4; ++i) {
      float mrow = 0.f;
      #pragma unroll
      for (int j = 0; j < 4; ++j) mrow = fmaxf(mrow, fabsf(vals[i][j]));
      #pragma unroll
      for (int off = 1; off < 16; off <<= 1) mrow = fmaxf(mrow, __shfl_xor(mrow, off));
      float s = mrow / 127.0f;
      if (s == 0.f) s = 1.f;
      const int r = row0 + ty * 4 + i;
      const int bidx = r / SEQ, sidx = r % SEQ;
      const size_t rowidx = ((size_t)bidx * NHEAD + h) * SEQ + sidx;
      unsigned int pack = 0;
      #pragma unroll
      for (int j = 0; j < 4; ++j) {
        float q = fminf(fmaxf(rintf(vals[i][j] / s), -127.f), 127.f);
        pack |= ((unsigned int)(unsigned char)(signed char)(int)q) << (8 * j);
      }
      *(unsigned int*)(qo + rowidx * HDIM + tx * 4) = pack;
      if (tx == 0) so[rowidx] = s;
    }
  } else {
    #pragma unroll
    for (int i = 0; i < 4; ++i) {
      const int r = row0 + ty * 4 + i;
      *(float4*)(fo + (size_t)r * HID + col0 + tx * 4) =
          make_float4(vals[i][0], vals[i][1], vals[i][2], vals[i][3]);
    }
  }
}

// -------- V transpose + fp16 convert: Vt[hb][d][k] = half(qv[k][d]*vs[k]) --
__global__ __launch_bounds__(256)
void v_transpose(const signed char* __restrict__ qv, const float* __restrict__ vss,
                 _Float16* __restrict__ vt) {
  __shared__ __align__(16) signed char tile[64][80];
  __shared__ float vsc[64];
  const int hb = blockIdx.y;
  const int k0 = blockIdx.x * 64;
  const int t = threadIdx.x;
  const int r = t >> 2, seg = t & 3;
  const int4 av = *(const int4*)(qv + ((size_t)hb * SEQ + k0 + r) * HDIM + seg * 16);
  *(int4*)&tile[r][seg * 16] = av;
  if (t < 64) vsc[t] = vss[(size_t)hb * SEQ + k0 + t];
  __syncthreads();
  const int d = t >> 2, ks = (t & 3) * 16;
  half8 h0, h1;
  #pragma unroll
  for (int j = 0; j < 8; ++j) {
    const int k = ks + j;
    h0[j] = (_Float16)((float)tile[k][d] * vsc[k]);
  }
  #pragma unroll
  for (int j = 0; j < 8; ++j) {
    const int k = ks + 8 + j;
    h1[j] = (_Float16)((float)tile[k][d] * vsc[k]);
  }
  _Float16* out = vt + ((size_t)hb * HDIM + d) * SEQ + k0 + ks;
  *(half8*)out = h0;
  *(half8*)(out + 8) = h1;
}

// ---------------- fused attention: MFMA QK^T -> PLA softmax -> MFMA PV ----
__global__ __launch_bounds__(256)
void attn_kernel(const signed char* __restrict__ qq, const float* __restrict__ qss,
                 const signed char* __restrict__ qk, const float* __restrict__ kss,
                 const _Float16* __restrict__ vth,
                 float* __restrict__ ctx, const PlaConsts pc) {
  __shared__ __align__(16) float sc[16][516];         // scores (fp32)
  __shared__ __align__(16) _Float16 PhT[16 * 16 * 32]; // [ktile32][row16][k32]
  __shared__ float kscale[512];
  __shared__ float qscale[16];
  __shared__ float rowmax4[4][16];
  __shared__ float psa[16];
  __shared__ float plm[12], plc[12], plb[13];

  const int tid = threadIdx.x;
  const int q0 = blockIdx.x * 16;
  const int hh = blockIdx.y, bz = blockIdx.z;
  const size_t hb = (size_t)bz * NHEAD + hh;
  const signed char* qqh = qq + (hb * SEQ + q0) * HDIM;
  const signed char* qkh = qk + hb * SEQ * HDIM;

  kscale[tid] = kss[hb * SEQ + tid];
  kscale[tid + 256] = kss[hb * SEQ + tid + 256];
  if (tid < 16) qscale[tid] = qss[hb * SEQ + q0 + tid];
  if (tid < 12) { plm[tid] = pc.m[tid]; plc[tid] = pc.c[tid]; }
  if (tid < 13) plb[tid] = pc.b[tid];
  __syncthreads();

  const int w = tid >> 6, lane = tid & 63;
  const int n = lane & 15, quad = lane >> 4;

  // ---- Phase 1: QK^T via i8 MFMA (exact int), scale, row-max ----
  {
    const v4i afrag = *(const v4i*)(qqh + (size_t)n * HDIM + quad * 16);
    float qs4[4];
    #pragma unroll
    for (int r = 0; r < 4; ++r) qs4[r] = qscale[quad * 4 + r] * 0.125f;
    float vmax[4] = {-3.0e38f, -3.0e38f, -3.0e38f, -3.0e38f};
    for (int t = 0; t < 8; ++t) {
      const int kc0 = (t * 4 + w) * 16;
      const v4i bfrag = *(const v4i*)(qkh + (size_t)(kc0 + n) * HDIM + quad * 16);
      v4i zero = {};
      const v4i acc = __builtin_amdgcn_mfma_i32_16x16x64_i8(afrag, bfrag, zero, 0, 0, 0);
      const float ksc = kscale[kc0 + n];
      #pragma unroll
      for (int r = 0; r < 4; ++r) {
        const float v = (float)acc[r] * (qs4[r] * ksc);
        sc[quad * 4 + r][kc0 + n] = v;
        vmax[r] = fmaxf(vmax[r], v);
      }
    }
    #pragma unroll
    for (int r = 0; r < 4; ++r) {
      #pragma unroll
      for (int off = 1; off < 16; off <<= 1)
        vmax[r] = fmaxf(vmax[r], __shfl_xor(vmax[r], off));
    }
    if (n == 0) {
      #pragma unroll
      for (int r = 0; r < 4; ++r) rowmax4[w][quad * 4 + r] = vmax[r];
    }
  }
  __syncthreads();

  // ---- Phase 2: PLA softmax + prob quantization (exps in registers) ----
  {
    const int qr = tid >> 4, ksl = tid & 15;
    const float mx = fmaxf(fmaxf(rowmax4[0][qr], rowmax4[1][qr]),
                           fmaxf(rowmax4[2][qr], rowmax4[3][qr]));
    float er[32];
    float sum = 0.f, amax = 0.f;
    #pragma unroll
    for (int jj = 0; jj < 16; ++jj) {
      const float2 s2 = *(const float2*)&sc[qr][jj * 32 + ksl * 2];
      #pragma unroll
      for (int u = 0; u < 2; ++u) {
        const float sh = (u ? s2.y : s2.x) - mx;
        float tq = rintf(sh * 67108864.0f);
        tq = fminf(fmaxf(tq, -2147483648.0f), 2147483648.0f);
        const float x = tq * (1.0f / 67108864.0f);
        const float xc = fminf(fmaxf(x, -10.0f), 0.0f);
        int g = (int)floorf((xc + 10.0f) * 1.2f);
        g = g < 0 ? 0 : (g > 11 ? 11 : g);
        if (xc < plb[g]) --g;
        else if (xc >= plb[g + 1]) ++g;
        g = g < 0 ? 0 : (g > 11 ? 11 : g);
        const float e = __fadd_rn(__fmul_rn(plm[g], xc), plc[g]);
        er[jj * 2 + u] = e;
        sum += e;
        amax = fmaxf(amax, fabsf(e));
      }
    }
    #pragma unroll
    for (int off = 1; off < 16; off <<= 1) {
      sum += __shfl_xor(sum, off);
      amax = fmaxf(amax, __shfl_xor(amax, off));
    }
    const float denom = __fadd_rn(sum, 1e-9f);
    const float rden = 1.0f / denom;
    float ps = (amax * rden) / 127.0f;
    if (ps == 0.f) ps = 1.f;
    const float rps = 1.0f / ps;
    if (ksl == 0) psa[qr] = ps;
    #pragma unroll
    for (int jj = 0; jj < 16; ++jj) {
      const float p0 = er[jj * 2 + 0] * rden;
      const float p1 = er[jj * 2 + 1] * rden;
      const float q0 = fminf(fmaxf(rintf(p0 * rps), -127.f), 127.f);
      const float q1 = fminf(fmaxf(rintf(p1 * rps), -127.f), 127.f);
      union { _Float16 h[2]; unsigned int u32; } pk;
      pk.h[0] = (_Float16)q0; pk.h[1] = (_Float16)q1;
      *(unsigned int*)&PhT[(jj * 16 + qr) * 32 + ksl * 2] = pk.u32;
    }
  }
  __syncthreads();

  // ---- Phase 3: PV via f16 MFMA (P=int qf exact; V has vs folded in) ----
  {
    v4f accf = {0.f, 0.f, 0.f, 0.f};
    const _Float16* vrow = vth + ((size_t)hb * HDIM + w * 16 + n) * SEQ + quad * 8;
    const _Float16* prow = &PhT[n * 32 + quad * 8];
    #pragma unroll 4
    for (int kt = 0; kt < 16; ++kt) {
      const half8 bf = *(const half8*)(vrow + kt * 32);
      const half8 af = *(const half8*)(prow + kt * 512);
      accf = __builtin_amdgcn_mfma_f32_16x16x32_f16(af, bf, accf, 0, 0, 0);
    }
    #pragma unroll
    for (int r = 0; r < 4; ++r) {
      const int row = quad * 4 + r;
      const float o = accf[r] * psa[row];
      ctx[((size_t)bz * SEQ + q0 + row) * HID + (size_t)hh * HDIM + w * 16 + n] = o;
    }
  }
}

// --------------------------------------------------------------------------
extern "C" void kernel_launch(void* const* d_in, const int* in_sizes, int n_in,
                              void* d_out, int out_size, void* d_ws, size_t ws_size,
                              hipStream_t stream) {
  (void)in_sizes; (void)n_in; (void)out_size; (void)ws_size;
  const float* hs = (const float*)d_in[0];
  const float* Wq = (const float*)d_in[1];
  const float* bq = (const float*)d_in[2];
  const float* Wk = (const float*)d_in[3];
  const float* bk = (const float*)d_in[4];
  const float* Wv = (const float*)d_in[5];
  const float* bv = (const float*)d_in[6];
  const float* Wo = (const float*)d_in[7];
  const float* bo = (const float*)d_in[8];
  float* out = (float*)d_out;

  char* ws = (char*)d_ws;
  size_t off = 0;
  auto alloc = [&](size_t bytes) -> char* {
    char* p = ws + off;
    off += (bytes + 255) & ~(size_t)255;
    return p;
  };
  signed char* qx  = (signed char*)alloc((size_t)R_TOT * HID);
  float*       sx  = (float*)alloc((size_t)R_TOT * 4);
  signed char* qwq = (signed char*)alloc((size_t)HID * HID);
  signed char* qwk = (signed char*)alloc((size_t)HID * HID);
  signed char* qwv = (signed char*)alloc((size_t)HID * HID);
  signed char* qwo = (signed char*)alloc((size_t)HID * HID);
  float*       swq = (float*)alloc((size_t)HID * 4);
  float*       swk = (float*)alloc((size_t)HID * 4);
  float*       swv = (float*)alloc((size_t)HID * 4);
  float*       swo = (float*)alloc((size_t)HID * 4);
  signed char* qqd = (signed char*)alloc((size_t)R_TOT * HID);
  float*       qqs = (float*)alloc((size_t)BATCH * NHEAD * SEQ * 4);
  signed char* qkd = (signed char*)alloc((size_t)R_TOT * HID);
  float*       qks = (float*)alloc((size_t)BATCH * NHEAD * SEQ * 4);
  signed char* qvd = (signed char*)alloc((size_t)R_TOT * HID);
  float*       qvs = (float*)alloc((size_t)BATCH * NHEAD * SEQ * 4);
  float*       ctx = (float*)alloc((size_t)R_TOT * HID * 4);
  _Float16*    vth = (_Float16*)alloc((size_t)BATCH * NHEAD * HDIM * SEQ * 2);
  // alias: qx/sx are dead after the V projection
  signed char* qc  = qx;
  float*       scs = sx;

  quant_rows<<<R_TOT, 256, 0, stream>>>(hs, HID, qx, sx);
  quant_rows<<<HID, 256, 0, stream>>>(Wq, HID, qwq, swq);
  quant_rows<<<HID, 256, 0, stream>>>(Wk, HID, qwk, swk);
  quant_rows<<<HID, 256, 0, stream>>>(Wv, HID, qwv, swv);
  quant_rows<<<HID, 256, 0, stream>>>(Wo, HID, qwo, swo);

  const dim3 pg(R_TOT / 64, HID / 64);
  proj_kernel<true><<<pg, 256, 0, stream>>>(qx, sx, qwq, swq, bq, qqd, qqs, nullptr);
  proj_kernel<true><<<pg, 256, 0, stream>>>(qx, sx, qwk, swk, bk, qkd, qks, nullptr);
  proj_kernel<true><<<pg, 256, 0, stream>>>(qx, sx, qwv, swv, bv, qvd, qvs, nullptr);

  v_transpose<<<dim3(SEQ / 64, BATCH * NHEAD), 256, 0, stream>>>(qvd, qvs, vth);

  attn_kernel<<<dim3(SEQ / 16, NHEAD, BATCH), 256, 0, stream>>>(
      qqd, qqs, qkd, qks, vth, ctx, g_pla);

  quant_rows<<<R_TOT, 256, 0, stream>>>(ctx, HID, qc, scs);
  proj_kernel<false><<<pg, 256, 0, stream>>>(qc, scs, qwo, swo, bo, nullptr, nullptr, out);
}

// Round 3
// 196.037 us; speedup vs baseline: 2.3092x; 1.3745x over previous
//
#include <hip/hip_runtime.h>
#include <cmath>

#define R_TOT 4096   // B*S rows
#define HID   768
#define NHEAD 12
#define HDIM  64
#define SEQ   512
#define BATCH 8

typedef int   v4i  __attribute__((ext_vector_type(4)));
typedef float v4f  __attribute__((ext_vector_type(4)));
typedef _Float16 half8 __attribute__((ext_vector_type(8)));

// ---------------- PLA coefficients (host, replicates np.polyfit in f64) ----
struct PlaConsts { float m[12]; float c[12]; float b[13]; };

static PlaConsts build_pla() {
  PlaConsts pc;
  const int NPTS = 1001;
  static double xs[NPTS], ys[NPTS];
  const double step = 10.0 / 1000.0;
  for (int j = 0; j < NPTS; ++j) xs[j] = (double)j * step + (-10.0);
  xs[NPTS - 1] = 0.0;
  for (int j = 0; j < NPTS; ++j) ys[j] = std::exp(xs[j]);
  double bnd[13];
  const double step2 = 10.0 / 12.0;
  for (int k = 0; k < 13; ++k) bnd[k] = (double)k * step2 + (-10.0);
  bnd[12] = 0.0;
  for (int i = 0; i < 12; ++i) {
    const double a = bnd[i], bb = bnd[i + 1];
    double sx = 0, sy = 0; int n = 0;
    for (int j = 0; j < NPTS; ++j)
      if (xs[j] >= a && xs[j] <= bb) { sx += xs[j]; sy += ys[j]; ++n; }
    const double xm = sx / n, ym = sy / n;
    double sxx = 0, sxy = 0;
    for (int j = 0; j < NPTS; ++j)
      if (xs[j] >= a && xs[j] <= bb) {
        const double dx = xs[j] - xm;
        sxx += dx * dx; sxy += dx * (ys[j] - ym);
      }
    const double m = sxy / sxx;
    pc.m[i] = (float)m;
    pc.c[i] = (float)(ym - m * xm);
  }
  for (int k = 0; k < 13; ++k) pc.b[k] = (float)bnd[k];
  return pc;
}
static const PlaConsts g_pla = build_pla();

// ---------------- per-row abs-max int8 quantization -----------------------
__global__ __launch_bounds__(256)
void quant_rows(const float* __restrict__ src, int ncols,
                signed char* __restrict__ qout, float* __restrict__ sout) {
  const int row = blockIdx.x;
  const float* x = src + (size_t)row * ncols;
  float m = 0.f;
  for (int c = threadIdx.x; c < ncols; c += 256)
    m = fmaxf(m, fabsf(x[c]));
  #pragma unroll
  for (int off = 32; off; off >>= 1) m = fmaxf(m, __shfl_xor(m, off));
  __shared__ float red[4];
  const int lane = threadIdx.x & 63, wv = threadIdx.x >> 6;
  if (lane == 0) red[wv] = m;
  __syncthreads();
  if (threadIdx.x == 0) {
    float mm = fmaxf(fmaxf(red[0], red[1]), fmaxf(red[2], red[3]));
    float s = mm / 127.0f;
    if (s == 0.f) s = 1.f;
    red[0] = s;
    sout[row] = s;
  }
  __syncthreads();
  const float s = red[0];
  for (int c = threadIdx.x; c < ncols; c += 256) {
    float q = rintf(x[c] / s);
    q = fminf(fmaxf(q, -127.f), 127.f);
    qout[(size_t)row * ncols + c] = (signed char)(int)q;
  }
}

// ---------------- int8 MFMA GEMM: out = (qx.qw^T)*sx*sw + bias ------------
// 64x64 tile, 4 waves x 16-row slab, K-chunks of 64, i8 MFMA 16x16x64.
template <bool HEADQ>
__global__ __launch_bounds__(256)
void proj_mfma(const signed char* __restrict__ qx, const float* __restrict__ sx,
               const signed char* __restrict__ qw, const float* __restrict__ sw,
               const float* __restrict__ bias,
               signed char* __restrict__ qo, float* __restrict__ so,
               float* __restrict__ fo) {
  __shared__ __align__(16) signed char Al[64 * 80];  // +16B row pad: 2-way max
  __shared__ __align__(16) signed char Bl[64 * 80];
  const int tid = threadIdx.x;
  const int w = tid >> 6, lane = tid & 63;
  const int n = lane & 15, quad = lane >> 4;
  const int row0 = blockIdx.x * 64, col0 = blockIdx.y * 64;
  const int lr = tid >> 2, seg = tid & 3;
  v4i acc[4];
  #pragma unroll
  for (int j = 0; j < 4; ++j) acc[j] = (v4i){0, 0, 0, 0};
  for (int k0 = 0; k0 < HID; k0 += 64) {
    const int4 av = *(const int4*)(qx + (size_t)(row0 + lr) * HID + k0 + seg * 16);
    const int4 bv = *(const int4*)(qw + (size_t)(col0 + lr) * HID + k0 + seg * 16);
    if (k0) __syncthreads();
    *(int4*)&Al[lr * 80 + seg * 16] = av;
    *(int4*)&Bl[lr * 80 + seg * 16] = bv;
    __syncthreads();
    const v4i af = *(const v4i*)&Al[(w * 16 + n) * 80 + quad * 16];
    #pragma unroll
    for (int j = 0; j < 4; ++j) {
      const v4i bf = *(const v4i*)&Bl[(j * 16 + n) * 80 + quad * 16];
      acc[j] = __builtin_amdgcn_mfma_i32_16x16x64_i8(af, bf, acc[j], 0, 0, 0);
    }
  }
  // lane(n,quad,w): out rows row0 + w*16 + quad*4 + r, cols col0 + j*16 + n
  const int mrow = w * 16 + quad * 4;
  float sxr[4];
  #pragma unroll
  for (int r = 0; r < 4; ++r) sxr[r] = sx[row0 + mrow + r];
  float vals[4][4];  // [j][r]
  #pragma unroll
  for (int j = 0; j < 4; ++j) {
    const float swc = sw[col0 + j * 16 + n];
    const float bc = bias[col0 + j * 16 + n];
    #pragma unroll
    for (int r = 0; r < 4; ++r)
      vals[j][r] = (float)acc[j][r] * (sxr[r] * swc) + bc;
  }
  if (HEADQ) {
    const int h = blockIdx.y;  // 64 cols == one head
    #pragma unroll
    for (int r = 0; r < 4; ++r) {
      float m = 0.f;
      #pragma unroll
      for (int j = 0; j < 4; ++j) m = fmaxf(m, fabsf(vals[j][r]));
      #pragma unroll
      for (int off = 1; off < 16; off <<= 1) m = fmaxf(m, __shfl_xor(m, off));
      float s = m / 127.0f;
      if (s == 0.f) s = 1.f;
      const int grow = row0 + mrow + r;
      const int bidx = grow / SEQ, sidx = grow % SEQ;
      const size_t rowidx = ((size_t)bidx * NHEAD + h) * SEQ + sidx;
      #pragma unroll
      for (int j = 0; j < 4; ++j) {
        float q = fminf(fmaxf(rintf(vals[j][r] / s), -127.f), 127.f);
        qo[rowidx * HDIM + j * 16 + n] = (signed char)(int)q;
      }
      if (n == 0) so[rowidx] = s;
    }
  } else {
    #pragma unroll
    for (int r = 0; r < 4; ++r) {
      const size_t base = (size_t)(row0 + mrow + r) * HID + col0;
      #pragma unroll
      for (int j = 0; j < 4; ++j)
        fo[base + j * 16 + n] = vals[j][r];
    }
  }
}

// -------- V transpose + fp16 convert: Vt[hb][d][k] = half(qv[k][d]*vs[k]) --
__global__ __launch_bounds__(256)
void v_transpose(const signed char* __restrict__ qv, const float* __restrict__ vss,
                 _Float16* __restrict__ vt) {
  __shared__ __align__(16) signed char tile[64][80];
  __shared__ float vsc[64];
  const int hb = blockIdx.y;
  const int k0 = blockIdx.x * 64;
  const int t = threadIdx.x;
  const int r = t >> 2, seg = t & 3;
  const int4 av = *(const int4*)(qv + ((size_t)hb * SEQ + k0 + r) * HDIM + seg * 16);
  *(int4*)&tile[r][seg * 16] = av;
  if (t < 64) vsc[t] = vss[(size_t)hb * SEQ + k0 + t];
  __syncthreads();
  const int d = t >> 2, ks = (t & 3) * 16;
  half8 h0, h1;
  #pragma unroll
  for (int j = 0; j < 8; ++j) {
    const int k = ks + j;
    h0[j] = (_Float16)((float)tile[k][d] * vsc[k]);
  }
  #pragma unroll
  for (int j = 0; j < 8; ++j) {
    const int k = ks + 8 + j;
    h1[j] = (_Float16)((float)tile[k][d] * vsc[k]);
  }
  _Float16* out = vt + ((size_t)hb * HDIM + d) * SEQ + k0 + ks;
  *(half8*)out = h0;
  *(half8*)(out + 8) = h1;
}

// ---------------- fused attention: MFMA QK^T -> reg softmax -> MFMA PV ----
#define PSTR 520  // PhT row stride in halves (512 + 8 pad)
__global__ __launch_bounds__(256)
void attn_kernel(const signed char* __restrict__ qq, const float* __restrict__ qss,
                 const signed char* __restrict__ qk, const float* __restrict__ kss,
                 const _Float16* __restrict__ vth,
                 float* __restrict__ ctx, const PlaConsts pc) {
  __shared__ __align__(16) _Float16 PhT[16 * PSTR];  // quantized probs, A-layout
  __shared__ float kscale[512];
  __shared__ float qscale[16];
  __shared__ float red_max[4][16], red_sum[4][16], red_amax[4][16];
  __shared__ float psa[16];
  __shared__ float plm[12], plc[12], plb[13];

  const int tid = threadIdx.x;
  const int q0 = blockIdx.x * 16;
  const int hh = blockIdx.y, bz = blockIdx.z;
  const size_t hb = (size_t)bz * NHEAD + hh;
  const signed char* qqh = qq + (hb * SEQ + q0) * HDIM;
  const signed char* qkh = qk + hb * SEQ * HDIM;

  kscale[tid] = kss[hb * SEQ + tid];
  kscale[tid + 256] = kss[hb * SEQ + tid + 256];
  if (tid < 16) qscale[tid] = qss[hb * SEQ + q0 + tid];
  if (tid < 12) { plm[tid] = pc.m[tid]; plc[tid] = pc.c[tid]; }
  if (tid < 13) plb[tid] = pc.b[tid];
  __syncthreads();

  const int w = tid >> 6, lane = tid & 63;
  const int n = lane & 15, quad = lane >> 4;
  const int row = quad * 4;  // +r

  // ---- Phase 1: QK^T via i8 MFMA (exact int); scores stay in registers ----
  float sval[8][4];   // [t][r]: score rows quad*4+r, col (t*4+w)*16+n
  {
    const v4i afrag = *(const v4i*)(qqh + (size_t)n * HDIM + quad * 16);
    float qs4[4];
    #pragma unroll
    for (int r = 0; r < 4; ++r) qs4[r] = qscale[row + r] * 0.125f;
    float vmax[4] = {-3.0e38f, -3.0e38f, -3.0e38f, -3.0e38f};
    #pragma unroll
    for (int t = 0; t < 8; ++t) {
      const int kc0 = (t * 4 + w) * 16;
      const v4i bfrag = *(const v4i*)(qkh + (size_t)(kc0 + n) * HDIM + quad * 16);
      v4i zero = {};
      const v4i acc = __builtin_amdgcn_mfma_i32_16x16x64_i8(afrag, bfrag, zero, 0, 0, 0);
      const float ksc = kscale[kc0 + n];
      #pragma unroll
      for (int r = 0; r < 4; ++r) {
        const float v = (float)acc[r] * (qs4[r] * ksc);
        sval[t][r] = v;
        vmax[r] = fmaxf(vmax[r], v);
      }
    }
    #pragma unroll
    for (int r = 0; r < 4; ++r) {
      #pragma unroll
      for (int off = 1; off < 16; off <<= 1)
        vmax[r] = fmaxf(vmax[r], __shfl_xor(vmax[r], off));
    }
    if (n == 0) {
      #pragma unroll
      for (int r = 0; r < 4; ++r) red_max[w][row + r] = vmax[r];
    }
  }
  __syncthreads();

  // ---- Phase 2: PLA softmax on registers, quantize, write PhT ----
  {
    float mx[4], sum[4] = {0, 0, 0, 0}, amax[4] = {0, 0, 0, 0};
    #pragma unroll
    for (int r = 0; r < 4; ++r)
      mx[r] = fmaxf(fmaxf(red_max[0][row + r], red_max[1][row + r]),
                    fmaxf(red_max[2][row + r], red_max[3][row + r]));
    #pragma unroll
    for (int t = 0; t < 8; ++t) {
      #pragma unroll
      for (int r = 0; r < 4; ++r) {
        const float sh = sval[t][r] - mx[r];
        float tq = rintf(sh * 67108864.0f);
        tq = fminf(fmaxf(tq, -2147483648.0f), 2147483648.0f);
        const float x = tq * (1.0f / 67108864.0f);
        const float xc = fminf(fmaxf(x, -10.0f), 0.0f);
        int g = (int)floorf((xc + 10.0f) * 1.2f);
        g = g < 0 ? 0 : (g > 11 ? 11 : g);
        if (xc < plb[g]) --g;
        else if (xc >= plb[g + 1]) ++g;
        g = g < 0 ? 0 : (g > 11 ? 11 : g);
        const float e = __fadd_rn(__fmul_rn(plm[g], xc), plc[g]);
        sval[t][r] = e;
        sum[r] += e;
        amax[r] = fmaxf(amax[r], fabsf(e));
      }
    }
    #pragma unroll
    for (int r = 0; r < 4; ++r) {
      #pragma unroll
      for (int off = 1; off < 16; off <<= 1) {
        sum[r] += __shfl_xor(sum[r], off);
        amax[r] = fmaxf(amax[r], __shfl_xor(amax[r], off));
      }
    }
    if (n == 0) {
      #pragma unroll
      for (int r = 0; r < 4; ++r) {
        red_sum[w][row + r] = sum[r];
        red_amax[w][row + r] = amax[r];
      }
    }
    __syncthreads();
    #pragma unroll
    for (int r = 0; r < 4; ++r) {
      const int rr = row + r;
      float denom = ((red_sum[0][rr] + red_sum[1][rr]) +
                     (red_sum[2][rr] + red_sum[3][rr]));
      denom = __fadd_rn(denom, 1e-9f);
      const float rden = 1.0f / denom;
      const float am = fmaxf(fmaxf(red_amax[0][rr], red_amax[1][rr]),
                             fmaxf(red_amax[2][rr], red_amax[3][rr]));
      float ps = (am * rden) / 127.0f;
      if (ps == 0.f) ps = 1.f;
      const float rps = 1.0f / ps;
      if (w == 0 && n == 0) psa[rr] = ps;
      #pragma unroll
      for (int t = 0; t < 8; ++t) {
        const float p = sval[t][r] * rden;
        const float qf = fminf(fmaxf(rintf(p * rps), -127.f), 127.f);
        PhT[rr * PSTR + (t * 4 + w) * 16 + n] = (_Float16)qf;
      }
    }
  }
  __syncthreads();

  // ---- Phase 3: PV via f16 MFMA (P=int qf exact; V has vs folded in) ----
  {
    v4f accf = {0.f, 0.f, 0.f, 0.f};
    const _Float16* vrow = vth + ((size_t)hb * HDIM + w * 16 + n) * SEQ + quad * 8;
    const _Float16* prow = &PhT[n * PSTR + quad * 8];
    #pragma unroll 4
    for (int kt = 0; kt < 16; ++kt) {
      const half8 bf = *(const half8*)(vrow + kt * 32);
      const half8 af = *(const half8*)(prow + kt * 32);
      accf = __builtin_amdgcn_mfma_f32_16x16x32_f16(af, bf, accf, 0, 0, 0);
    }
    #pragma unroll
    for (int r = 0; r < 4; ++r) {
      const float o = accf[r] * psa[row + r];
      ctx[((size_t)bz * SEQ + q0 + row + r) * HID + (size_t)hh * HDIM + w * 16 + n] = o;
    }
  }
}

// --------------------------------------------------------------------------
extern "C" void kernel_launch(void* const* d_in, const int* in_sizes, int n_in,
                              void* d_out, int out_size, void* d_ws, size_t ws_size,
                              hipStream_t stream) {
  (void)in_sizes; (void)n_in; (void)out_size; (void)ws_size;
  const float* hs = (const float*)d_in[0];
  const float* Wq = (const float*)d_in[1];
  const float* bq = (const float*)d_in[2];
  const float* Wk = (const float*)d_in[3];
  const float* bk = (const float*)d_in[4];
  const float* Wv = (const float*)d_in[5];
  const float* bv = (const float*)d_in[6];
  const float* Wo = (const float*)d_in[7];
  const float* bo = (const float*)d_in[8];
  float* out = (float*)d_out;

  char* ws = (char*)d_ws;
  size_t off = 0;
  auto alloc = [&](size_t bytes) -> char* {
    char* p = ws + off;
    off += (bytes + 255) & ~(size_t)255;
    return p;
  };
  signed char* qx  = (signed char*)alloc((size_t)R_TOT * HID);
  float*       sx  = (float*)alloc((size_t)R_TOT * 4);
  signed char* qwq = (signed char*)alloc((size_t)HID * HID);
  signed char* qwk = (signed char*)alloc((size_t)HID * HID);
  signed char* qwv = (signed char*)alloc((size_t)HID * HID);
  signed char* qwo = (signed char*)alloc((size_t)HID * HID);
  float*       swq = (float*)alloc((size_t)HID * 4);
  float*       swk = (float*)alloc((size_t)HID * 4);
  float*       swv = (float*)alloc((size_t)HID * 4);
  float*       swo = (float*)alloc((size_t)HID * 4);
  signed char* qqd = (signed char*)alloc((size_t)R_TOT * HID);
  float*       qqs = (float*)alloc((size_t)BATCH * NHEAD * SEQ * 4);
  signed char* qkd = (signed char*)alloc((size_t)R_TOT * HID);
  float*       qks = (float*)alloc((size_t)BATCH * NHEAD * SEQ * 4);
  signed char* qvd = (signed char*)alloc((size_t)R_TOT * HID);
  float*       qvs = (float*)alloc((size_t)BATCH * NHEAD * SEQ * 4);
  float*       ctx = (float*)alloc((size_t)R_TOT * HID * 4);
  _Float16*    vth = (_Float16*)alloc((size_t)BATCH * NHEAD * HDIM * SEQ * 2);
  // alias: qx/sx are dead after the V projection
  signed char* qc  = qx;
  float*       scs = sx;

  quant_rows<<<R_TOT, 256, 0, stream>>>(hs, HID, qx, sx);
  quant_rows<<<HID, 256, 0, stream>>>(Wq, HID, qwq, swq);
  quant_rows<<<HID, 256, 0, stream>>>(Wk, HID, qwk, swk);
  quant_rows<<<HID, 256, 0, stream>>>(Wv, HID, qwv, swv);
  quant_rows<<<HID, 256, 0, stream>>>(Wo, HID, qwo, swo);

  const dim3 pg(R_TOT / 64, HID / 64);
  proj_mfma<true><<<pg, 256, 0, stream>>>(qx, sx, qwq, swq, bq, qqd, qqs, nullptr);
  proj_mfma<true><<<pg, 256, 0, stream>>>(qx, sx, qwk, swk, bk, qkd, qks, nullptr);
  proj_mfma<true><<<pg, 256, 0, stream>>>(qx, sx, qwv, swv, bv, qvd, qvs, nullptr);

  v_transpose<<<dim3(SEQ / 64, BATCH * NHEAD), 256, 0, stream>>>(qvd, qvs, vth);

  attn_kernel<<<dim3(SEQ / 16, NHEAD, BATCH), 256, 0, stream>>>(
      qqd, qqs, qkd, qks, vth, ctx, g_pla);

  quant_rows<<<R_TOT, 256, 0, stream>>>(ctx, HID, qc, scs);
  proj_mfma<false><<<pg, 256, 0, stream>>>(qc, scs, qwo, swo, bo, nullptr, nullptr, out);
}

// Round 4
// 179.659 us; speedup vs baseline: 2.5198x; 1.0912x over previous
//
#include <hip/hip_runtime.h>
#include <cmath>

#define R_TOT 4096   // B*S rows
#define HID   768
#define NHEAD 12
#define HDIM  64
#define SEQ   512
#define BATCH 8

typedef int   v4i  __attribute__((ext_vector_type(4)));
typedef float v4f  __attribute__((ext_vector_type(4)));
typedef _Float16 half8 __attribute__((ext_vector_type(8)));
typedef _Float16 half4v __attribute__((ext_vector_type(4)));

// ---------------- PLA coefficients (host, replicates np.polyfit in f64) ----
struct PlaConsts { float m[12]; float c[12]; float b[13]; };

static PlaConsts build_pla() {
  PlaConsts pc;
  const int NPTS = 1001;
  static double xs[NPTS], ys[NPTS];
  const double step = 10.0 / 1000.0;
  for (int j = 0; j < NPTS; ++j) xs[j] = (double)j * step + (-10.0);
  xs[NPTS - 1] = 0.0;
  for (int j = 0; j < NPTS; ++j) ys[j] = std::exp(xs[j]);
  double bnd[13];
  const double step2 = 10.0 / 12.0;
  for (int k = 0; k < 13; ++k) bnd[k] = (double)k * step2 + (-10.0);
  bnd[12] = 0.0;
  for (int i = 0; i < 12; ++i) {
    const double a = bnd[i], bb = bnd[i + 1];
    double sx = 0, sy = 0; int n = 0;
    for (int j = 0; j < NPTS; ++j)
      if (xs[j] >= a && xs[j] <= bb) { sx += xs[j]; sy += ys[j]; ++n; }
    const double xm = sx / n, ym = sy / n;
    double sxx = 0, sxy = 0;
    for (int j = 0; j < NPTS; ++j)
      if (xs[j] >= a && xs[j] <= bb) {
        const double dx = xs[j] - xm;
        sxx += dx * dx; sxy += dx * (ys[j] - ym);
      }
    const double m = sxy / sxx;
    pc.m[i] = (float)m;
    pc.c[i] = (float)(ym - m * xm);
  }
  for (int k = 0; k < 13; ++k) pc.b[k] = (float)bnd[k];
  return pc;
}
static const PlaConsts g_pla = build_pla();

// ---------------- per-row abs-max int8 quantization -----------------------
__device__ __forceinline__ void quant_row_body(const float* __restrict__ x,
                                               signed char* __restrict__ qrow,
                                               float* __restrict__ srow,
                                               int ncols) {
  float m = 0.f;
  for (int c = threadIdx.x; c < ncols; c += 256)
    m = fmaxf(m, fabsf(x[c]));
  #pragma unroll
  for (int off = 32; off; off >>= 1) m = fmaxf(m, __shfl_xor(m, off));
  __shared__ float red[4];
  const int lane = threadIdx.x & 63, wv = threadIdx.x >> 6;
  if (lane == 0) red[wv] = m;
  __syncthreads();
  if (threadIdx.x == 0) {
    float mm = fmaxf(fmaxf(red[0], red[1]), fmaxf(red[2], red[3]));
    float s = mm / 127.0f;
    if (s == 0.f) s = 1.f;
    red[0] = s;
    *srow = s;
  }
  __syncthreads();
  const float s = red[0];
  for (int c = threadIdx.x; c < ncols; c += 256) {
    float q = rintf(x[c] / s);
    q = fminf(fmaxf(q, -127.f), 127.f);
    qrow[c] = (signed char)(int)q;
  }
}

__global__ __launch_bounds__(256)
void quant_rows(const float* __restrict__ src, int ncols,
                signed char* __restrict__ qout, float* __restrict__ sout) {
  const int row = blockIdx.x;
  quant_row_body(src + (size_t)row * ncols, qout + (size_t)row * ncols,
                 sout + row, ncols);
}

// 4 weight matrices in one launch (grid.y selects)
__global__ __launch_bounds__(256)
void quant_w4(const float* w0, const float* w1, const float* w2, const float* w3,
              signed char* q0, signed char* q1, signed char* q2, signed char* q3,
              float* s0, float* s1, float* s2, float* s3) {
  const int row = blockIdx.x;
  const float* src; signed char* qo; float* so;
  switch (blockIdx.y) {
    case 0: src = w0; qo = q0; so = s0; break;
    case 1: src = w1; qo = q1; so = s1; break;
    case 2: src = w2; qo = q2; so = s2; break;
    default: src = w3; qo = q3; so = s3; break;
  }
  quant_row_body(src + (size_t)row * HID, qo + (size_t)row * HID, so + row, HID);
}

// ---------------- int8 MFMA GEMM: out = (qx.qw^T)*sx*sw + bias ------------
// MODE 0: fp32 dense out; MODE 1: per-head int8 quant out (bhsd);
// MODE 2: V path — fp16 transposed out vt[hb][d][k] = half(qint*scale)
template <int MODE>
__global__ __launch_bounds__(256)
void proj_mfma(const signed char* __restrict__ qx, const float* __restrict__ sx,
               const signed char* __restrict__ qw, const float* __restrict__ sw,
               const float* __restrict__ bias,
               signed char* __restrict__ qo, float* __restrict__ so,
               _Float16* __restrict__ vt, float* __restrict__ fo) {
  __shared__ __align__(16) signed char Al[64 * 80];  // +16B row pad: 2-way max
  __shared__ __align__(16) signed char Bl[64 * 80];
  const int tid = threadIdx.x;
  const int w = tid >> 6, lane = tid & 63;
  const int n = lane & 15, quad = lane >> 4;
  const int row0 = blockIdx.x * 64, col0 = blockIdx.y * 64;
  const int lr = tid >> 2, seg = tid & 3;
  v4i acc[4];
  #pragma unroll
  for (int j = 0; j < 4; ++j) acc[j] = (v4i){0, 0, 0, 0};
  for (int k0 = 0; k0 < HID; k0 += 64) {
    const int4 av = *(const int4*)(qx + (size_t)(row0 + lr) * HID + k0 + seg * 16);
    const int4 bv = *(const int4*)(qw + (size_t)(col0 + lr) * HID + k0 + seg * 16);
    if (k0) __syncthreads();
    *(int4*)&Al[lr * 80 + seg * 16] = av;
    *(int4*)&Bl[lr * 80 + seg * 16] = bv;
    __syncthreads();
    const v4i af = *(const v4i*)&Al[(w * 16 + n) * 80 + quad * 16];
    #pragma unroll
    for (int j = 0; j < 4; ++j) {
      const v4i bf = *(const v4i*)&Bl[(j * 16 + n) * 80 + quad * 16];
      acc[j] = __builtin_amdgcn_mfma_i32_16x16x64_i8(af, bf, acc[j], 0, 0, 0);
    }
  }
  // lane(n,quad,w): out rows row0 + w*16 + quad*4 + r, cols col0 + j*16 + n
  const int mrow = w * 16 + quad * 4;
  float sxr[4];
  #pragma unroll
  for (int r = 0; r < 4; ++r) sxr[r] = sx[row0 + mrow + r];
  float vals[4][4];  // [j][r]
  #pragma unroll
  for (int j = 0; j < 4; ++j) {
    const float swc = sw[col0 + j * 16 + n];
    const float bc = bias[col0 + j * 16 + n];
    #pragma unroll
    for (int r = 0; r < 4; ++r)
      vals[j][r] = (float)acc[j][r] * (sxr[r] * swc) + bc;
  }
  if (MODE == 1) {
    const int h = blockIdx.y;  // 64 cols == one head
    #pragma unroll
    for (int r = 0; r < 4; ++r) {
      float m = 0.f;
      #pragma unroll
      for (int j = 0; j < 4; ++j) m = fmaxf(m, fabsf(vals[j][r]));
      #pragma unroll
      for (int off = 1; off < 16; off <<= 1) m = fmaxf(m, __shfl_xor(m, off));
      float s = m / 127.0f;
      if (s == 0.f) s = 1.f;
      const int grow = row0 + mrow + r;
      const int bidx = grow >> 9, sidx = grow & 511;
      const size_t rowidx = ((size_t)bidx * NHEAD + h) * SEQ + sidx;
      #pragma unroll
      for (int j = 0; j < 4; ++j) {
        float q = fminf(fmaxf(rintf(vals[j][r] / s), -127.f), 127.f);
        qo[rowidx * HDIM + j * 16 + n] = (signed char)(int)q;
      }
      if (n == 0) so[rowidx] = s;
    }
  } else if (MODE == 2) {
    const int h = blockIdx.y;
    float srow[4];
    #pragma unroll
    for (int r = 0; r < 4; ++r) {
      float m = 0.f;
      #pragma unroll
      for (int j = 0; j < 4; ++j) m = fmaxf(m, fabsf(vals[j][r]));
      #pragma unroll
      for (int off = 1; off < 16; off <<= 1) m = fmaxf(m, __shfl_xor(m, off));
      float s = m / 127.0f;
      if (s == 0.f) s = 1.f;
      srow[r] = s;
    }
    const int grow0 = row0 + mrow;          // 4 consecutive k (same batch)
    const int bidx = grow0 >> 9, sidx = grow0 & 511;
    const size_t hbv = (size_t)bidx * NHEAD + h;
    #pragma unroll
    for (int j = 0; j < 4; ++j) {
      half4v hv;
      #pragma unroll
      for (int r = 0; r < 4; ++r) {
        float q = fminf(fmaxf(rintf(vals[j][r] / srow[r]), -127.f), 127.f);
        hv[r] = (_Float16)(q * srow[r]);
      }
      *(half4v*)(vt + (hbv * HDIM + j * 16 + n) * SEQ + sidx) = hv;
    }
  } else {
    #pragma unroll
    for (int r = 0; r < 4; ++r) {
      const size_t base = (size_t)(row0 + mrow + r) * HID + col0;
      #pragma unroll
      for (int j = 0; j < 4; ++j)
        fo[base + j * 16 + n] = vals[j][r];
    }
  }
}

// ---------------- fused attention: MFMA S^T -> row-per-lane softmax -> PV --
#define PSTR 520  // PhT row stride in halves (512 + 8 pad)
__global__ __launch_bounds__(256)
void attn_kernel(const signed char* __restrict__ qq, const float* __restrict__ qss,
                 const signed char* __restrict__ qk, const float* __restrict__ kss,
                 const _Float16* __restrict__ vth,
                 float* __restrict__ ctx, const PlaConsts pc) {
  __shared__ __align__(16) _Float16 PhT[16 * PSTR];  // quantized probs [q][k]
  __shared__ __align__(16) float red_max[16][4], red_sum[16][4], red_amax[16][4];
  __shared__ float psa[16];
  __shared__ __align__(8) float pb2[12][2];  // (b[i], b[i+1])
  __shared__ __align__(8) float pmc[12][2];  // (m[i], c[i])

  const int tid = threadIdx.x;
  const int q0 = blockIdx.x * 16;
  const int hh = blockIdx.y, bz = blockIdx.z;
  const size_t hb = (size_t)bz * NHEAD + hh;
  const signed char* qqh = qq + (hb * SEQ + q0) * HDIM;
  const signed char* qkh = qk + hb * SEQ * HDIM;
  const float* ksp = kss + hb * SEQ;

  if (tid < 12) {
    pb2[tid][0] = pc.b[tid]; pb2[tid][1] = pc.b[tid + 1];
    pmc[tid][0] = pc.m[tid]; pmc[tid][1] = pc.c[tid];
  }

  const int w = tid >> 6, lane = tid & 63;
  const int n = lane & 15, quad = lane >> 4;

  // ---- Phase 1: S^T via i8 MFMA (A=K rows, B=Q rows) ----
  // lane(n,quad) reg r holds S[q-row n][key (t*4+w)*16 + quad*4 + r], *2^26
  float s26[8][4];
  {
    const v4i qfrag = *(const v4i*)(qqh + (size_t)n * HDIM + quad * 16);
    const float qs26 = (qss[hb * SEQ + q0 + n] * 0.125f) * 67108864.0f;
    float vmax = -3.0e38f;
    #pragma unroll
    for (int t = 0; t < 8; ++t) {
      const int kc0 = (t * 4 + w) * 16;
      const v4i kfrag = *(const v4i*)(qkh + (size_t)(kc0 + n) * HDIM + quad * 16);
      const float4 ks4 = *(const float4*)(ksp + kc0 + quad * 4);
      v4i zero = {};
      const v4i acc = __builtin_amdgcn_mfma_i32_16x16x64_i8(kfrag, qfrag, zero, 0, 0, 0);
      const float ks[4] = {ks4.x, ks4.y, ks4.z, ks4.w};
      #pragma unroll
      for (int r = 0; r < 4; ++r) {
        const float v = (float)acc[r] * (qs26 * ks[r]);
        s26[t][r] = v;
        vmax = fmaxf(vmax, v);
      }
    }
    vmax = fmaxf(vmax, __shfl_xor(vmax, 16));
    vmax = fmaxf(vmax, __shfl_xor(vmax, 32));
    if (quad == 0) red_max[n][w] = vmax;
  }
  __syncthreads();

  // ---- Phase 2: PLA softmax (one row per lane), quantize, pack to PhT ----
  {
    const float4 rm = *(const float4*)&red_max[n][0];
    const float mx26 = fmaxf(fmaxf(rm.x, rm.y), fmaxf(rm.z, rm.w));
    float sum = 0.f, amax = 0.f;
    #pragma unroll
    for (int t = 0; t < 8; ++t) {
      #pragma unroll
      for (int r = 0; r < 4; ++r) {
        float sh = s26[t][r] - mx26;            // == (s-mx)*2^26 exactly
        sh = fmaxf(sh, -671088640.0f);          // clamp at -10*2^26
        const float tq = rintf(sh);
        const float xc = tq * 1.4901161193847656e-08f;  // *2^-26 (exact)
        int g = (int)floorf((xc + 10.0f) * 1.2f);
        g = g < 0 ? 0 : (g > 11 ? 11 : g);
        const float2 bb = *(const float2*)&pb2[g][0];
        if (xc < bb.x) --g;
        else if (xc >= bb.y) ++g;
        g = g < 0 ? 0 : (g > 11 ? 11 : g);
        const float2 mc = *(const float2*)&pmc[g][0];
        const float e = __fadd_rn(__fmul_rn(mc.x, xc), mc.y);
        s26[t][r] = e;
        sum += e;
        amax = fmaxf(amax, fabsf(e));
      }
    }
    sum += __shfl_xor(sum, 16);
    sum += __shfl_xor(sum, 32);
    amax = fmaxf(amax, __shfl_xor(amax, 16));
    amax = fmaxf(amax, __shfl_xor(amax, 32));
    if (quad == 0) { red_sum[n][w] = sum; red_amax[n][w] = amax; }
    __syncthreads();
    const float4 rs = *(const float4*)&red_sum[n][0];
    const float4 ra = *(const float4*)&red_amax[n][0];
    float denom = (rs.x + rs.y) + (rs.z + rs.w);
    denom = __fadd_rn(denom, 1e-9f);
    const float rden = 1.0f / denom;
    const float am = fmaxf(fmaxf(ra.x, ra.y), fmaxf(ra.z, ra.w));
    float ps = (am * rden) / 127.0f;
    if (ps == 0.f) ps = 1.f;
    const float rps = 1.0f / ps;
    if (w == 0 && quad == 0) psa[n] = ps;
    #pragma unroll
    for (int t = 0; t < 8; ++t) {
      half4v hq;
      #pragma unroll
      for (int r = 0; r < 4; ++r) {
        const float p = s26[t][r] * rden;
        const float qf = fminf(fmaxf(rintf(p * rps), -127.f), 127.f);
        hq[r] = (_Float16)qf;
      }
      *(half4v*)&PhT[n * PSTR + (t * 4 + w) * 16 + quad * 4] = hq;
    }
  }
  __syncthreads();

  // ---- Phase 3: PV via f16 MFMA (P=int qf exact; V has vs folded in) ----
  {
    v4f accf = {0.f, 0.f, 0.f, 0.f};
    const _Float16* vrow = vth + ((size_t)hb * HDIM + w * 16 + n) * SEQ + quad * 8;
    const _Float16* prow = &PhT[n * PSTR + quad * 8];
    #pragma unroll 4
    for (int kt = 0; kt < 16; ++kt) {
      const half8 bf = *(const half8*)(vrow + kt * 32);
      const half8 af = *(const half8*)(prow + kt * 32);
      accf = __builtin_amdgcn_mfma_f32_16x16x32_f16(af, bf, accf, 0, 0, 0);
    }
    #pragma unroll
    for (int r = 0; r < 4; ++r) {
      const int row = quad * 4 + r;
      const float o = accf[r] * psa[row];
      ctx[((size_t)bz * SEQ + q0 + row) * HID + (size_t)hh * HDIM + w * 16 + n] = o;
    }
  }
}

// --------------------------------------------------------------------------
extern "C" void kernel_launch(void* const* d_in, const int* in_sizes, int n_in,
                              void* d_out, int out_size, void* d_ws, size_t ws_size,
                              hipStream_t stream) {
  (void)in_sizes; (void)n_in; (void)out_size; (void)ws_size;
  const float* hs = (const float*)d_in[0];
  const float* Wq = (const float*)d_in[1];
  const float* bq = (const float*)d_in[2];
  const float* Wk = (const float*)d_in[3];
  const float* bk = (const float*)d_in[4];
  const float* Wv = (const float*)d_in[5];
  const float* bv = (const float*)d_in[6];
  const float* Wo = (const float*)d_in[7];
  const float* bo = (const float*)d_in[8];
  float* out = (float*)d_out;

  char* ws = (char*)d_ws;
  size_t off = 0;
  auto alloc = [&](size_t bytes) -> char* {
    char* p = ws + off;
    off += (bytes + 255) & ~(size_t)255;
    return p;
  };
  signed char* qx  = (signed char*)alloc((size_t)R_TOT * HID);
  float*       sx  = (float*)alloc((size_t)R_TOT * 4);
  signed char* qwq = (signed char*)alloc((size_t)HID * HID);
  signed char* qwk = (signed char*)alloc((size_t)HID * HID);
  signed char* qwv = (signed char*)alloc((size_t)HID * HID);
  signed char* qwo = (signed char*)alloc((size_t)HID * HID);
  float*       swq = (float*)alloc((size_t)HID * 4);
  float*       swk = (float*)alloc((size_t)HID * 4);
  float*       swv = (float*)alloc((size_t)HID * 4);
  float*       swo = (float*)alloc((size_t)HID * 4);
  signed char* qqd = (signed char*)alloc((size_t)R_TOT * HID);
  float*       qqs = (float*)alloc((size_t)BATCH * NHEAD * SEQ * 4);
  signed char* qkd = (signed char*)alloc((size_t)R_TOT * HID);
  float*       qks = (float*)alloc((size_t)BATCH * NHEAD * SEQ * 4);
  float*       ctx = (float*)alloc((size_t)R_TOT * HID * 4);
  _Float16*    vth = (_Float16*)alloc((size_t)BATCH * NHEAD * HDIM * SEQ * 2);
  // alias: qx/sx are dead after the V projection
  signed char* qc  = qx;
  float*       scs = sx;

  quant_rows<<<R_TOT, 256, 0, stream>>>(hs, HID, qx, sx);
  quant_w4<<<dim3(HID, 4), 256, 0, stream>>>(Wq, Wk, Wv, Wo,
                                             qwq, qwk, qwv, qwo,
                                             swq, swk, swv, swo);

  const dim3 pg(R_TOT / 64, HID / 64);
  proj_mfma<1><<<pg, 256, 0, stream>>>(qx, sx, qwq, swq, bq, qqd, qqs, nullptr, nullptr);
  proj_mfma<1><<<pg, 256, 0, stream>>>(qx, sx, qwk, swk, bk, qkd, qks, nullptr, nullptr);
  proj_mfma<2><<<pg, 256, 0, stream>>>(qx, sx, qwv, swv, bv, nullptr, nullptr, vth, nullptr);

  attn_kernel<<<dim3(SEQ / 16, NHEAD, BATCH), 256, 0, stream>>>(
      qqd, qqs, qkd, qks, vth, ctx, g_pla);

  quant_rows<<<R_TOT, 256, 0, stream>>>(ctx, HID, qc, scs);
  proj_mfma<0><<<pg, 256, 0, stream>>>(qc, scs, qwo, swo, bo, nullptr, nullptr, nullptr, out);
}

// Round 5
// 166.067 us; speedup vs baseline: 2.7260x; 1.0818x over previous
//
#include <hip/hip_runtime.h>
#include <cmath>

#define R_TOT 4096   // B*S rows
#define HID   768
#define NHEAD 12
#define HDIM  64
#define SEQ   512
#define BATCH 8

typedef int   v4i  __attribute__((ext_vector_type(4)));
typedef float v4f  __attribute__((ext_vector_type(4)));
typedef _Float16 half8 __attribute__((ext_vector_type(8)));
typedef _Float16 half4v __attribute__((ext_vector_type(4)));

// ---------------- PLA coefficients (host, replicates np.polyfit in f64) ----
struct PlaConsts { float m[12]; float c[12]; float b[13]; };

static PlaConsts build_pla() {
  PlaConsts pc;
  const int NPTS = 1001;
  static double xs[NPTS], ys[NPTS];
  const double step = 10.0 / 1000.0;
  for (int j = 0; j < NPTS; ++j) xs[j] = (double)j * step + (-10.0);
  xs[NPTS - 1] = 0.0;
  for (int j = 0; j < NPTS; ++j) ys[j] = std::exp(xs[j]);
  double bnd[13];
  const double step2 = 10.0 / 12.0;
  for (int k = 0; k < 13; ++k) bnd[k] = (double)k * step2 + (-10.0);
  bnd[12] = 0.0;
  for (int i = 0; i < 12; ++i) {
    const double a = bnd[i], bb = bnd[i + 1];
    double sx = 0, sy = 0; int n = 0;
    for (int j = 0; j < NPTS; ++j)
      if (xs[j] >= a && xs[j] <= bb) { sx += xs[j]; sy += ys[j]; ++n; }
    const double xm = sx / n, ym = sy / n;
    double sxx = 0, sxy = 0;
    for (int j = 0; j < NPTS; ++j)
      if (xs[j] >= a && xs[j] <= bb) {
        const double dx = xs[j] - xm;
        sxx += dx * dx; sxy += dx * (ys[j] - ym);
      }
    const double m = sxy / sxx;
    pc.m[i] = (float)m;
    pc.c[i] = (float)(ym - m * xm);
  }
  for (int k = 0; k < 13; ++k) pc.b[k] = (float)bnd[k];
  return pc;
}
static const PlaConsts g_pla = build_pla();

// ---------------- per-row abs-max int8 quantization -----------------------
__device__ __forceinline__ void quant_row_body(const float* __restrict__ x,
                                               signed char* __restrict__ qrow,
                                               float* __restrict__ srow,
                                               int ncols) {
  float m = 0.f;
  for (int c = threadIdx.x; c < ncols; c += 256)
    m = fmaxf(m, fabsf(x[c]));
  #pragma unroll
  for (int off = 32; off; off >>= 1) m = fmaxf(m, __shfl_xor(m, off));
  __shared__ float red[4];
  const int lane = threadIdx.x & 63, wv = threadIdx.x >> 6;
  if (lane == 0) red[wv] = m;
  __syncthreads();
  if (threadIdx.x == 0) {
    float mm = fmaxf(fmaxf(red[0], red[1]), fmaxf(red[2], red[3]));
    float s = mm / 127.0f;
    if (s == 0.f) s = 1.f;
    red[0] = s;
    *srow = s;
  }
  __syncthreads();
  const float s = red[0];
  for (int c = threadIdx.x; c < ncols; c += 256) {
    float q = rintf(x[c] / s);
    q = fminf(fmaxf(q, -127.f), 127.f);
    qrow[c] = (signed char)(int)q;
  }
}

__global__ __launch_bounds__(256)
void quant_rows(const float* __restrict__ src, int ncols,
                signed char* __restrict__ qout, float* __restrict__ sout) {
  const int row = blockIdx.x;
  quant_row_body(src + (size_t)row * ncols, qout + (size_t)row * ncols,
                 sout + row, ncols);
}

__global__ __launch_bounds__(256)
void quant_w4(const float* w0, const float* w1, const float* w2, const float* w3,
              signed char* q0, signed char* q1, signed char* q2, signed char* q3,
              float* s0, float* s1, float* s2, float* s3) {
  const int row = blockIdx.x;
  const float* src; signed char* qo; float* so;
  switch (blockIdx.y) {
    case 0: src = w0; qo = q0; so = s0; break;
    case 1: src = w1; qo = q1; so = s1; break;
    case 2: src = w2; qo = q2; so = s2; break;
    default: src = w3; qo = q3; so = s3; break;
  }
  quant_row_body(src + (size_t)row * HID, qo + (size_t)row * HID, so + row, HID);
}

// ---------------- int8 MFMA GEMM body: 128x64 tile, 8 MFMA / barrier-pair --
// mode 0: fp32 dense out; mode 1: per-head int8 (bhsd) + scales;
// mode 2: V path -> fp16 k-chunked transposed vt2[hb][k>>5][d][k&31]
__device__ __forceinline__
void proj_body(int mode,
               const signed char* __restrict__ qx, const float* __restrict__ sx,
               const signed char* __restrict__ qw, const float* __restrict__ sw,
               const float* __restrict__ bias,
               signed char* __restrict__ qo, float* __restrict__ so,
               _Float16* __restrict__ vt, float* __restrict__ fo,
               signed char* Al, signed char* Bl) {
  const int tid = threadIdx.x;
  const int w = tid >> 6, lane = tid & 63;
  const int n = lane & 15, quad = lane >> 4;
  const int row0 = blockIdx.x * 128, col0 = blockIdx.y * 64;
  const int ar = tid >> 1, aseg = (tid & 1) * 32;
  const int br = tid >> 2, bseg = (tid & 3) * 16;
  v4i acc[2][4];
  #pragma unroll
  for (int s = 0; s < 2; ++s)
    #pragma unroll
    for (int j = 0; j < 4; ++j) acc[s][j] = (v4i){0, 0, 0, 0};
  for (int k0 = 0; k0 < HID; k0 += 64) {
    const int4 a0 = *(const int4*)(qx + (size_t)(row0 + ar) * HID + k0 + aseg);
    const int4 a1 = *(const int4*)(qx + (size_t)(row0 + ar) * HID + k0 + aseg + 16);
    const int4 b0 = *(const int4*)(qw + (size_t)(col0 + br) * HID + k0 + bseg);
    if (k0) __syncthreads();
    *(int4*)&Al[ar * 80 + aseg] = a0;
    *(int4*)&Al[ar * 80 + aseg + 16] = a1;
    *(int4*)&Bl[br * 80 + bseg] = b0;
    __syncthreads();
    const v4i af0 = *(const v4i*)&Al[(w * 16 + n) * 80 + quad * 16];
    const v4i af1 = *(const v4i*)&Al[(64 + w * 16 + n) * 80 + quad * 16];
    #pragma unroll
    for (int j = 0; j < 4; ++j) {
      const v4i bf = *(const v4i*)&Bl[(j * 16 + n) * 80 + quad * 16];
      acc[0][j] = __builtin_amdgcn_mfma_i32_16x16x64_i8(af0, bf, acc[0][j], 0, 0, 0);
      acc[1][j] = __builtin_amdgcn_mfma_i32_16x16x64_i8(af1, bf, acc[1][j], 0, 0, 0);
    }
  }
  float swc4[4], bc4[4];
  #pragma unroll
  for (int j = 0; j < 4; ++j) {
    swc4[j] = sw[col0 + j * 16 + n];
    bc4[j] = bias[col0 + j * 16 + n];
  }
  #pragma unroll
  for (int s = 0; s < 2; ++s) {
    const int mrow = s * 64 + w * 16 + quad * 4;
    float sxr[4];
    #pragma unroll
    for (int r = 0; r < 4; ++r) sxr[r] = sx[row0 + mrow + r];
    float vals[4][4];  // [j][r]
    #pragma unroll
    for (int j = 0; j < 4; ++j)
      #pragma unroll
      for (int r = 0; r < 4; ++r)
        vals[j][r] = (float)acc[s][j][r] * (sxr[r] * swc4[j]) + bc4[j];
    if (mode == 1) {
      const int h = blockIdx.y;
      #pragma unroll
      for (int r = 0; r < 4; ++r) {
        float m = 0.f;
        #pragma unroll
        for (int j = 0; j < 4; ++j) m = fmaxf(m, fabsf(vals[j][r]));
        #pragma unroll
        for (int off = 1; off < 16; off <<= 1) m = fmaxf(m, __shfl_xor(m, off));
        float sq = m / 127.0f;
        if (sq == 0.f) sq = 1.f;
        const int grow = row0 + mrow + r;
        const int bidx = grow >> 9, sidx = grow & 511;
        const size_t rowidx = ((size_t)bidx * NHEAD + h) * SEQ + sidx;
        #pragma unroll
        for (int j = 0; j < 4; ++j) {
          float q = fminf(fmaxf(rintf(vals[j][r] / sq), -127.f), 127.f);
          qo[rowidx * HDIM + j * 16 + n] = (signed char)(int)q;
        }
        if (n == 0) so[rowidx] = sq;
      }
    } else if (mode == 2) {
      const int h = blockIdx.y;
      float srow[4];
      #pragma unroll
      for (int r = 0; r < 4; ++r) {
        float m = 0.f;
        #pragma unroll
        for (int j = 0; j < 4; ++j) m = fmaxf(m, fabsf(vals[j][r]));
        #pragma unroll
        for (int off = 1; off < 16; off <<= 1) m = fmaxf(m, __shfl_xor(m, off));
        float sq = m / 127.0f;
        if (sq == 0.f) sq = 1.f;
        srow[r] = sq;
      }
      const int grow0 = row0 + mrow;         // 4 consecutive k, same batch
      const int bidx = grow0 >> 9, sidx = grow0 & 511;
      const int kb = sidx >> 5, ko = sidx & 31;
      const size_t hbv = (size_t)bidx * NHEAD + h;
      #pragma unroll
      for (int j = 0; j < 4; ++j) {
        half4v hv;
        #pragma unroll
        for (int r = 0; r < 4; ++r) {
          float q = fminf(fmaxf(rintf(vals[j][r] / srow[r]), -127.f), 127.f);
          hv[r] = (_Float16)(q * srow[r]);
        }
        *(half4v*)(vt + ((hbv * 16 + kb) * 64 + j * 16 + n) * 32 + ko) = hv;
      }
    } else {
      #pragma unroll
      for (int r = 0; r < 4; ++r) {
        const size_t base = (size_t)(row0 + mrow + r) * HID + col0;
        #pragma unroll
        for (int j = 0; j < 4; ++j)
          fo[base + j * 16 + n] = vals[j][r];
      }
    }
  }
}

// fused Q/K/V projections: blockIdx.z selects weight/output
__global__ __launch_bounds__(256)
void proj_qkv(const signed char* __restrict__ qx, const float* __restrict__ sx,
              const signed char* qwq, const float* swq, const float* bq,
              signed char* qqd, float* qqs,
              const signed char* qwk, const float* swk, const float* bk,
              signed char* qkd, float* qks,
              const signed char* qwv, const float* swv, const float* bv,
              _Float16* vt2) {
  __shared__ __align__(16) signed char Al[128 * 80];
  __shared__ __align__(16) signed char Bl[64 * 80];
  if (blockIdx.z == 0)
    proj_body(1, qx, sx, qwq, swq, bq, qqd, qqs, nullptr, nullptr, Al, Bl);
  else if (blockIdx.z == 1)
    proj_body(1, qx, sx, qwk, swk, bk, qkd, qks, nullptr, nullptr, Al, Bl);
  else
    proj_body(2, qx, sx, qwv, swv, bv, nullptr, nullptr, vt2, nullptr, Al, Bl);
}

__global__ __launch_bounds__(256)
void proj_out(const signed char* __restrict__ qx, const float* __restrict__ sx,
              const signed char* qw, const float* sw, const float* bias,
              float* fo) {
  __shared__ __align__(16) signed char Al[128 * 80];
  __shared__ __align__(16) signed char Bl[64 * 80];
  proj_body(0, qx, sx, qw, sw, bias, nullptr, nullptr, nullptr, fo, Al, Bl);
}

// ---------------- fused attention: 32 q-rows/block, dual-tile -------------
#define PSTR 520  // PhT row stride in halves (16B-aligned rows)
__global__ __launch_bounds__(256)
void attn_kernel(const signed char* __restrict__ qq, const float* __restrict__ qss,
                 const signed char* __restrict__ qk, const float* __restrict__ kss,
                 const _Float16* __restrict__ vt2,
                 float* __restrict__ ctx, const PlaConsts pc) {
  __shared__ __align__(16) _Float16 PhT[2 * 16 * PSTR];  // quantized probs
  __shared__ __align__(16) float red_max[2][16][4];
  __shared__ __align__(16) float red_sum[2][16][4];
  __shared__ __align__(16) float red_amax[2][16][4];
  __shared__ float psa[2][16];
  __shared__ __align__(8) float pb2[12][2];
  __shared__ __align__(8) float pmc[12][2];

  const int tid = threadIdx.x;
  const int q0 = blockIdx.x * 32;
  const int hh = blockIdx.y, bz = blockIdx.z;
  const size_t hb = (size_t)bz * NHEAD + hh;
  const signed char* qqh = qq + (hb * SEQ + q0) * HDIM;
  const signed char* qkh = qk + hb * SEQ * HDIM;
  const float* ksp = kss + hb * SEQ;

  if (tid < 12) {
    pb2[tid][0] = pc.b[tid]; pb2[tid][1] = pc.b[tid + 1];
    pmc[tid][0] = pc.m[tid]; pmc[tid][1] = pc.c[tid];
  }

  const int w = tid >> 6, lane = tid & 63;
  const int n = lane & 15, quad = lane >> 4;

  // ---- Phase 1: S^T via i8 MFMA (A=K rows, B=Q rows), two q-tiles ----
  float s26[2][8][4];
  {
    const v4i qf0 = *(const v4i*)(qqh + (size_t)n * HDIM + quad * 16);
    const v4i qf1 = *(const v4i*)(qqh + (size_t)(16 + n) * HDIM + quad * 16);
    const float qs0 = (qss[hb * SEQ + q0 + n] * 0.125f) * 67108864.0f;
    const float qs1 = (qss[hb * SEQ + q0 + 16 + n] * 0.125f) * 67108864.0f;
    float vmax0 = -3.0e38f, vmax1 = -3.0e38f;
    #pragma unroll
    for (int t = 0; t < 8; ++t) {
      const int kc0 = (t * 4 + w) * 16;
      const v4i kfrag = *(const v4i*)(qkh + (size_t)(kc0 + n) * HDIM + quad * 16);
      const float4 ks4 = *(const float4*)(ksp + kc0 + quad * 4);
      v4i zero = {};
      const v4i a0 = __builtin_amdgcn_mfma_i32_16x16x64_i8(kfrag, qf0, zero, 0, 0, 0);
      const v4i a1 = __builtin_amdgcn_mfma_i32_16x16x64_i8(kfrag, qf1, zero, 0, 0, 0);
      const float ks[4] = {ks4.x, ks4.y, ks4.z, ks4.w};
      #pragma unroll
      for (int r = 0; r < 4; ++r) {
        const float v0 = (float)a0[r] * (qs0 * ks[r]);
        const float v1 = (float)a1[r] * (qs1 * ks[r]);
        s26[0][t][r] = v0; vmax0 = fmaxf(vmax0, v0);
        s26[1][t][r] = v1; vmax1 = fmaxf(vmax1, v1);
      }
    }
    vmax0 = fmaxf(vmax0, __shfl_xor(vmax0, 16));
    vmax0 = fmaxf(vmax0, __shfl_xor(vmax0, 32));
    vmax1 = fmaxf(vmax1, __shfl_xor(vmax1, 16));
    vmax1 = fmaxf(vmax1, __shfl_xor(vmax1, 32));
    if (quad == 0) { red_max[0][n][w] = vmax0; red_max[1][n][w] = vmax1; }
  }
  __syncthreads();

  // ---- Phase 2a: PLA exp (one row per lane per tile), partial sums ----
  #pragma unroll
  for (int tau = 0; tau < 2; ++tau) {
    const float4 rm = *(const float4*)&red_max[tau][n][0];
    const float mx26 = fmaxf(fmaxf(rm.x, rm.y), fmaxf(rm.z, rm.w));
    float sum = 0.f, amax = 0.f;
    #pragma unroll
    for (int t = 0; t < 8; ++t) {
      #pragma unroll
      for (int r = 0; r < 4; ++r) {
        float sh = s26[tau][t][r] - mx26;       // == (s-mx)*2^26 exactly
        sh = fmaxf(sh, -671088640.0f);          // clamp at -10*2^26
        const float tq = rintf(sh);
        const float xc = tq * 1.4901161193847656e-08f;  // *2^-26 (exact)
        int g = (int)floorf((xc + 10.0f) * 1.2f);
        g = g < 0 ? 0 : (g > 11 ? 11 : g);
        const float2 bb = *(const float2*)&pb2[g][0];
        if (xc < bb.x) --g;
        else if (xc >= bb.y) ++g;
        g = g < 0 ? 0 : (g > 11 ? 11 : g);
        const float2 mc = *(const float2*)&pmc[g][0];
        const float e = __fadd_rn(__fmul_rn(mc.x, xc), mc.y);
        s26[tau][t][r] = e;
        sum += e;
        amax = fmaxf(amax, fabsf(e));
      }
    }
    sum += __shfl_xor(sum, 16);
    sum += __shfl_xor(sum, 32);
    amax = fmaxf(amax, __shfl_xor(amax, 16));
    amax = fmaxf(amax, __shfl_xor(amax, 32));
    if (quad == 0) { red_sum[tau][n][w] = sum; red_amax[tau][n][w] = amax; }
  }
  __syncthreads();

  // ---- Phase 2b: normalize, quantize, pack to PhT ----
  #pragma unroll
  for (int tau = 0; tau < 2; ++tau) {
    const float4 rs = *(const float4*)&red_sum[tau][n][0];
    const float4 ra = *(const float4*)&red_amax[tau][n][0];
    float denom = (rs.x + rs.y) + (rs.z + rs.w);
    denom = __fadd_rn(denom, 1e-9f);
    const float rden = 1.0f / denom;
    const float am = fmaxf(fmaxf(ra.x, ra.y), fmaxf(ra.z, ra.w));
    float ps = (am * rden) / 127.0f;
    if (ps == 0.f) ps = 1.f;
    const float rps = 1.0f / ps;
    if (w == 0 && quad == 0) psa[tau][n] = ps;
    #pragma unroll
    for (int t = 0; t < 8; ++t) {
      half4v hq;
      #pragma unroll
      for (int r = 0; r < 4; ++r) {
        const float p = s26[tau][t][r] * rden;
        const float qf = fminf(fmaxf(rintf(p * rps), -127.f), 127.f);
        hq[r] = (_Float16)qf;
      }
      *(half4v*)&PhT[(tau * 16 + n) * PSTR + (t * 4 + w) * 16 + quad * 4] = hq;
    }
  }
  __syncthreads();

  // ---- Phase 3: PV via f16 MFMA, coalesced V (k-chunked layout) ----
  {
    v4f acc0 = {0.f, 0.f, 0.f, 0.f}, acc1 = {0.f, 0.f, 0.f, 0.f};
    const _Float16* vbase = vt2 + ((size_t)hb * 16 * 64 + (w * 16 + n)) * 32 + quad * 8;
    const _Float16* p0 = &PhT[n * PSTR + quad * 8];
    const _Float16* p1 = &PhT[(16 + n) * PSTR + quad * 8];
    #pragma unroll 4
    for (int kt = 0; kt < 16; ++kt) {
      const half8 bf = *(const half8*)(vbase + kt * 2048);
      acc0 = __builtin_amdgcn_mfma_f32_16x16x32_f16(*(const half8*)(p0 + kt * 32), bf, acc0, 0, 0, 0);
      acc1 = __builtin_amdgcn_mfma_f32_16x16x32_f16(*(const half8*)(p1 + kt * 32), bf, acc1, 0, 0, 0);
    }
    #pragma unroll
    for (int r = 0; r < 4; ++r) {
      const int row = quad * 4 + r;
      const size_t cbase = (size_t)hh * HDIM + w * 16 + n;
      ctx[((size_t)bz * SEQ + q0 + row) * HID + cbase] = acc0[r] * psa[0][row];
      ctx[((size_t)bz * SEQ + q0 + 16 + row) * HID + cbase] = acc1[r] * psa[1][row];
    }
  }
}

// --------------------------------------------------------------------------
extern "C" void kernel_launch(void* const* d_in, const int* in_sizes, int n_in,
                              void* d_out, int out_size, void* d_ws, size_t ws_size,
                              hipStream_t stream) {
  (void)in_sizes; (void)n_in; (void)out_size; (void)ws_size;
  const float* hs = (const float*)d_in[0];
  const float* Wq = (const float*)d_in[1];
  const float* bq = (const float*)d_in[2];
  const float* Wk = (const float*)d_in[3];
  const float* bk = (const float*)d_in[4];
  const float* Wv = (const float*)d_in[5];
  const float* bv = (const float*)d_in[6];
  const float* Wo = (const float*)d_in[7];
  const float* bo = (const float*)d_in[8];
  float* out = (float*)d_out;

  char* ws = (char*)d_ws;
  size_t off = 0;
  auto alloc = [&](size_t bytes) -> char* {
    char* p = ws + off;
    off += (bytes + 255) & ~(size_t)255;
    return p;
  };
  signed char* qx  = (signed char*)alloc((size_t)R_TOT * HID);
  float*       sx  = (float*)alloc((size_t)R_TOT * 4);
  signed char* qwq = (signed char*)alloc((size_t)HID * HID);
  signed char* qwk = (signed char*)alloc((size_t)HID * HID);
  signed char* qwv = (signed char*)alloc((size_t)HID * HID);
  signed char* qwo = (signed char*)alloc((size_t)HID * HID);
  float*       swq = (float*)alloc((size_t)HID * 4);
  float*       swk = (float*)alloc((size_t)HID * 4);
  float*       swv = (float*)alloc((size_t)HID * 4);
  float*       swo = (float*)alloc((size_t)HID * 4);
  signed char* qqd = (signed char*)alloc((size_t)R_TOT * HID);
  float*       qqs = (float*)alloc((size_t)BATCH * NHEAD * SEQ * 4);
  signed char* qkd = (signed char*)alloc((size_t)R_TOT * HID);
  float*       qks = (float*)alloc((size_t)BATCH * NHEAD * SEQ * 4);
  float*       ctx = (float*)alloc((size_t)R_TOT * HID * 4);
  _Float16*    vt2 = (_Float16*)alloc((size_t)BATCH * NHEAD * HDIM * SEQ * 2);
  // alias: qx/sx are dead after the QKV projections
  signed char* qc  = qx;
  float*       scs = sx;

  quant_rows<<<R_TOT, 256, 0, stream>>>(hs, HID, qx, sx);
  quant_w4<<<dim3(HID, 4), 256, 0, stream>>>(Wq, Wk, Wv, Wo,
                                             qwq, qwk, qwv, qwo,
                                             swq, swk, swv, swo);

  proj_qkv<<<dim3(R_TOT / 128, HID / 64, 3), 256, 0, stream>>>(
      qx, sx, qwq, swq, bq, qqd, qqs,
      qwk, swk, bk, qkd, qks,
      qwv, swv, bv, vt2);

  attn_kernel<<<dim3(SEQ / 32, NHEAD, BATCH), 256, 0, stream>>>(
      qqd, qqs, qkd, qks, vt2, ctx, g_pla);

  quant_rows<<<R_TOT, 256, 0, stream>>>(ctx, HID, qc, scs);
  proj_out<<<dim3(R_TOT / 128, HID / 64), 256, 0, stream>>>(
      qc, scs, qwo, swo, bo, out);
}